// Round 1
// baseline (2140.565 us; speedup 1.0000x reference)
//
#include <hip/hip_runtime.h>
#include <math.h>

// ---------------- problem constants ----------------
#define BATCH 2
#define CCH   128
#define H1    96
#define W1    96
#define H2    48
#define W2    48
#define LP    2304   // H2*W2
#define K1    1152   // CCH*9   (3x3 im2col depth)
#define M2    2048   // CCH*16  (4x4 transpose-conv rows)

// ---------------- workspace layout (floats) ----------------
#define OFF_U   0u          // [2304][2304]  scores -> logits -> P (in place)
#define OFF_A   5308416u    // [1152][2304]  im2col of x2 (K-major)
#define OFF_RWT 7962624u    // [2304][2048]  raw_w transposed (c rows, m cols)
#define OFF_Z   12681216u   // [2048][2304]
#define OFF_Y   17399808u   // [2][128][96][96]
#define OFF_MS  19759104u   // [2][48*48] downsampled mask
#define OFF_MA  19763712u   // [2][48*48] downsampled mask_all
#define OFF_MM  19768320u   // [2][2304]  valid-patch flag
#define OFF_NRM 19772928u   // [2304]
#define WS_FLOATS 19775232u

// ---------------- bilinear resize (exact jnp.linspace replication) ----------
// jax linspace(0,95,48): s_i = fl(i/47), ys_i = fl(95*s_i) for i<47, ys_47 = 95.
__device__ __forceinline__ float lin_coord(int i) {
    if (i == 47) return 95.0f;
    return __fmul_rn(95.0f, __fdiv_rn((float)i, 47.0f));
}

__global__ void resize_masks(const float* __restrict__ mask,
                             const float* __restrict__ mask_all,
                             float* __restrict__ ms, float* __restrict__ ma) {
    int idx = blockIdx.x * 256 + threadIdx.x;
    if (idx >= BATCH * LP) return;
    int b = idx / LP, r = idx % LP;
    int i = r / W2, j = r % W2;
    float ys = lin_coord(i), xs = lin_coord(j);
    int y0 = (int)ys; int y1 = min(y0 + 1, 95);
    int x0 = (int)xs; int x1 = min(x0 + 1, 95);
    float wy = __fsub_rn(ys, (float)y0);
    float wx = __fsub_rn(xs, (float)x0);
    float wy1 = __fsub_rn(1.0f, wy), wx1 = __fsub_rn(1.0f, wx);
    const float* mb = mask + b * H1 * W1;
    float t0 = __fadd_rn(__fmul_rn(mb[y0*W1+x0], wy1), __fmul_rn(mb[y1*W1+x0], wy));
    float t1 = __fadd_rn(__fmul_rn(mb[y0*W1+x1], wy1), __fmul_rn(mb[y1*W1+x1], wy));
    ms[idx] = __fadd_rn(__fmul_rn(t0, wx1), __fmul_rn(t1, wx));
    const float* ab = mask_all + b * H1 * W1;
    t0 = __fadd_rn(__fmul_rn(ab[y0*W1+x0], wy1), __fmul_rn(ab[y1*W1+x0], wy));
    t1 = __fadd_rn(__fmul_rn(ab[y0*W1+x1], wy1), __fmul_rn(ab[y1*W1+x1], wy));
    ma[idx] = __fadd_rn(__fmul_rn(t0, wx1), __fmul_rn(t1, wx));
}

// mm[b,c] = 1 iff all 9 (zero-padded) 3x3 neighbors of mask_s are exactly 0.
// (mask_s >= 0 everywhere, so mean==0 <=> every element ==0.)
__global__ void compute_mm(const float* __restrict__ ms, float* __restrict__ mm) {
    int idx = blockIdx.x * 256 + threadIdx.x;
    if (idx >= BATCH * LP) return;
    int b = idx / LP, r = idx % LP;
    int ci = r / W2, cj = r % W2;
    const float* m = ms + b * LP;
    bool any = false;
    #pragma unroll
    for (int di = -1; di <= 1; ++di)
        #pragma unroll
        for (int dj = -1; dj <= 1; ++dj) {
            int y = ci + di, x = cj + dj;
            if ((unsigned)y < H2 && (unsigned)x < W2)
                any = any || (m[y*W2 + x] > 0.0f);
        }
    mm[idx] = any ? 0.0f : 1.0f;
}

// A[k][p] = x2p[ch, i+dy, j+dx]  (pad 1), k = ch*9 + dy*3 + dx, p = i*48+j
__global__ void im2col_x2(const float* __restrict__ x2, float* __restrict__ A) {
    int idx = blockIdx.x * 256 + threadIdx.x;
    if (idx >= K1 * LP) return;
    int k = idx / LP, p = idx % LP;
    int ch = k / 9, t = k % 9, dy = t / 3, dx = t % 3;
    int i = p / W2, j = p % W2;
    int y = i + dy - 1, x = j + dx - 1;
    float v = 0.0f;
    if ((unsigned)y < H2 && (unsigned)x < W2) v = x2[ch*LP + y*W2 + x];
    A[idx] = v;
}

// RwT[c][m] = x1p[ch, 2*ci+ky, 2*cj+kx] (pad 1), m = ch*16 + ky*4 + kx
__global__ void build_rwt(const float* __restrict__ x1, float* __restrict__ RwT) {
    int idx = blockIdx.x * 256 + threadIdx.x;
    if (idx >= LP * M2) return;
    int c = idx >> 11, m = idx & 2047;
    int ci = c / W2, cj = c % W2;
    int ch = m >> 4, kk = m & 15, ky = kk >> 2, kx = kk & 3;
    int y = 2*ci + ky - 1, x = 2*cj + kx - 1;
    float v = 0.0f;
    if ((unsigned)y < H1 && (unsigned)x < W1) v = x1[ch*H1*W1 + y*W1 + x];
    RwT[idx] = v;
}

// ---------------- fp32 SGEMM: C[m][n] = sum_k A[k][m] * B[k][n] ----------------
// A: [K][M] lda=M, B: [K][N] ldb=N, C: [M][N].  M,N % 128 == 0, K % 8 == 0.
// SYM: A==B square case -> compute upper-triangle blocks, mirror the tile.
template <bool SYM>
__global__ __launch_bounds__(256) void gemm_tn(const float* __restrict__ A,
                                               const float* __restrict__ B,
                                               float* __restrict__ C,
                                               int M, int N, int K) {
    int bx = blockIdx.x, by = blockIdx.y;
    if (SYM && by > bx) return;
    __shared__ float As[8][128];
    __shared__ float Bs[8][128];
    const int bm = by * 128, bn = bx * 128;
    const int tid = threadIdx.x;
    const int tx = tid & 15, ty = tid >> 4;
    const int lr = tid >> 5;          // 0..7 (k row)
    const int lc = (tid & 31) * 4;    // 0..124 (col, float4)
    const float* Aptr = A + lr * M + bm + lc;
    const float* Bptr = B + lr * N + bn + lc;
    float4 pa = *(const float4*)Aptr;
    float4 pb = *(const float4*)Bptr;
    float acc[8][8] = {};
    const int nk = K >> 3;
    for (int ks = 0; ks < nk; ++ks) {
        *(float4*)&As[lr][lc] = pa;
        *(float4*)&Bs[lr][lc] = pb;
        __syncthreads();
        if (ks + 1 < nk) {
            pa = *(const float4*)(Aptr + (ks + 1) * 8 * M);
            pb = *(const float4*)(Bptr + (ks + 1) * 8 * N);
        }
        #pragma unroll
        for (int kk = 0; kk < 8; ++kk) {
            float af[8], bf[8];
            #pragma unroll
            for (int i = 0; i < 8; ++i) af[i] = As[kk][ty*8 + i];
            #pragma unroll
            for (int j = 0; j < 8; ++j) bf[j] = Bs[kk][tx*8 + j];
            #pragma unroll
            for (int i = 0; i < 8; ++i)
                #pragma unroll
                for (int j = 0; j < 8; ++j)
                    acc[i][j] = fmaf(af[i], bf[j], acc[i][j]);
        }
        __syncthreads();
    }
    float* Cp = C + (bm + ty*8) * N + bn + tx*8;
    #pragma unroll
    for (int i = 0; i < 8; ++i) {
        *(float4*)&Cp[i*N + 0] = make_float4(acc[i][0], acc[i][1], acc[i][2], acc[i][3]);
        *(float4*)&Cp[i*N + 4] = make_float4(acc[i][4], acc[i][5], acc[i][6], acc[i][7]);
    }
    if (SYM && bx != by) {  // mirror tile (values identical by commutativity)
        #pragma unroll
        for (int i = 0; i < 8; ++i)
            #pragma unroll
            for (int j = 0; j < 8; ++j)
                C[(bn + tx*8 + j) * N + (bm + ty*8 + i)] = acc[i][j];
    }
}

// nrm[c] = max(sqrt(U[c][c]), 1e-4)
__global__ void diag_norm(const float* __restrict__ U, float* __restrict__ nrm) {
    int c = blockIdx.x * 256 + threadIdx.x;
    if (c >= LP) return;
    nrm[c] = fmaxf(sqrtf(U[c * LP + c]), 1e-4f);
}

// Column softmax + masking + neighbor boost + clip, in place on U.
// Block: 64 columns x 4 row-groups.
__global__ __launch_bounds__(256) void softmax_col(float* __restrict__ U,
                                                   const float* __restrict__ nrm,
                                                   const float* __restrict__ mm,
                                                   const float* __restrict__ mamap) {
    __shared__ float redM[4][64];
    __shared__ float redS[4][64];
    const int tx = threadIdx.x & 63, tg = threadIdx.x >> 6;
    const int p = blockIdx.x * 64 + tx;
    const float maF = mamap[p];
    const int pi = p / W2, pj = p % W2;
    float mx = -INFINITY, sm = 0.0f;
    for (int c = tg; c < LP; c += 4) {
        float t = (((U[c*LP + p] / nrm[c]) * mm[c]) * maF) * 10.0f;
        U[c*LP + p] = t;   // cache logit for pass 2
        float nmx = fmaxf(mx, t);
        sm = sm * __expf(mx - nmx) + __expf(t - nmx);
        mx = nmx;
    }
    redM[tg][tx] = mx; redS[tg][tx] = sm;
    __syncthreads();
    float Mx = fmaxf(fmaxf(redM[0][tx], redM[1][tx]), fmaxf(redM[2][tx], redM[3][tx]));
    float S  = redS[0][tx]*__expf(redM[0][tx]-Mx) + redS[1][tx]*__expf(redM[1][tx]-Mx)
             + redS[2][tx]*__expf(redM[2][tx]-Mx) + redS[3][tx]*__expf(redM[3][tx]-Mx);
    for (int c = tg; c < LP; c += 4) {
        float t = U[c*LP + p];
        float r = __expf(t - Mx) / S;
        int ci = c / W2, cj = c - ci*W2;
        if (abs(ci - pi) + abs(cj - pj) == 1) r = r + r * 0.5f;
        r = (r * mm[c]) * maF;
        U[c*LP + p] = fmaxf(r, 1e-8f);
    }
}

// y[b][ch][yy][xx] = 0.25 * sum over valid (ky,kx) of Z[(ch,ky,kx)][i*48+j],
// where yy = 2i+ky-1, xx = 2j+kx-1  (conv_transpose stride 2 pad 1, kernel 4)
__global__ void scatter_y(const float* __restrict__ Z, float* __restrict__ y) {
    int idx = blockIdx.x * 256 + threadIdx.x;
    if (idx >= CCH * H1 * W1) return;
    int ch = idx / (H1*W1), r = idx % (H1*W1);
    int yy = r / W1, xx = r % W1;
    float s = 0.0f;
    #pragma unroll
    for (int ky = 0; ky < 4; ++ky) {
        int ny = yy + 1 - ky;
        if (ny & 1) continue;
        int i = ny >> 1;
        if ((unsigned)i >= H2) continue;
        #pragma unroll
        for (int kx = 0; kx < 4; ++kx) {
            int nx = xx + 1 - kx;
            if (nx & 1) continue;
            int j = nx >> 1;
            if ((unsigned)j >= W2) continue;
            s += Z[(ch*16 + ky*4 + kx) * LP + i*W2 + j];
        }
    }
    y[idx] = s * 0.25f;
}

// 4 dilated 3x3 convs (dilation 1,2,4,8; "same"), +bias, relu, concat.
// Block = (b, g, 16x16 spatial tile); thread = 1 pixel x 16 out-channels.
// Weights are wave-uniform -> scalar loads + v_fma with SGPR operand.
__global__ __launch_bounds__(256) void dilated_conv(const float* __restrict__ y,
                                                    const float* __restrict__ w,
                                                    const float* __restrict__ bias,
                                                    float* __restrict__ out) {
    int bid = blockIdx.x;                 // b*4*36 + g*36 + tile
    int tile = bid % 36; int g = (bid / 36) % 4; int b = bid / 144;
    int yy = (tile / 6) * 16 + (threadIdx.x >> 4);
    int xx = (tile % 6) * 16 + (threadIdx.x & 15);
    int rr = 1 << g;                      // RATES = 1,2,4,8
    const float* yb = y + b * CCH * H1 * W1;
    const float* wg = w + g * 16 * CCH * 9;
    float acc[16] = {};
    for (int ic = 0; ic < CCH; ++ic) {
        const float* yc = yb + ic * H1 * W1;
        #pragma unroll
        for (int t = 0; t < 9; ++t) {
            int sy = yy + rr * (t / 3 - 1), sx = xx + rr * (t % 3 - 1);
            float v = 0.0f;
            if ((unsigned)sy < H1 && (unsigned)sx < W1) v = yc[sy*W1 + sx];
            #pragma unroll
            for (int oc = 0; oc < 16; ++oc)
                acc[oc] = fmaf(v, wg[(oc*CCH + ic)*9 + t], acc[oc]);
        }
    }
    #pragma unroll
    for (int oc = 0; oc < 16; ++oc) {
        float o = fmaxf(acc[oc] + bias[g*16 + oc], 0.0f);
        out[(size_t)((b*64 + g*16 + oc) * (H1*W1)) + yy*W1 + xx] = o;
    }
}

extern "C" void kernel_launch(void* const* d_in, const int* in_sizes, int n_in,
                              void* d_out, int out_size, void* d_ws, size_t ws_size,
                              hipStream_t stream) {
    if (ws_size < (size_t)WS_FLOATS * 4) return;  // insufficient scratch -> fail loudly
    const float* x1       = (const float*)d_in[0];
    const float* x2       = (const float*)d_in[1];
    const float* mask     = (const float*)d_in[2];
    const float* mask_all = (const float*)d_in[3];
    const float* conv_w   = (const float*)d_in[4];
    const float* conv_b   = (const float*)d_in[5];
    float* ws  = (float*)d_ws;
    float* U   = ws + OFF_U;
    float* A   = ws + OFF_A;
    float* RWT = ws + OFF_RWT;
    float* Z   = ws + OFF_Z;
    float* Y   = ws + OFF_Y;
    float* MS  = ws + OFF_MS;
    float* MA  = ws + OFF_MA;
    float* MM  = ws + OFF_MM;
    float* NRM = ws + OFF_NRM;

    resize_masks<<<18, 256, 0, stream>>>(mask, mask_all, MS, MA);
    compute_mm<<<18, 256, 0, stream>>>(MS, MM);

    for (int b = 0; b < BATCH; ++b) {
        im2col_x2<<<(K1 * LP) / 256, 256, 0, stream>>>(x2 + (size_t)b * CCH * LP, A);
        gemm_tn<true><<<dim3(18, 18), 256, 0, stream>>>(A, A, U, LP, LP, K1);
        diag_norm<<<9, 256, 0, stream>>>(U, NRM);
        softmax_col<<<36, 256, 0, stream>>>(U, NRM, MM + b * LP, MA + b * LP);
        build_rwt<<<(LP * M2) / 256, 256, 0, stream>>>(x1 + (size_t)b * CCH * H1 * W1, RWT);
        gemm_tn<false><<<dim3(18, 16), 256, 0, stream>>>(RWT, U, Z, M2, LP, LP);
        scatter_y<<<(CCH * H1 * W1) / 256, 256, 0, stream>>>(Z, Y + (size_t)b * CCH * H1 * W1);
    }
    dilated_conv<<<288, 256, 0, stream>>>(Y, conv_w, conv_b, (float*)d_out);
}

// Round 2
// 1531.733 us; speedup vs baseline: 1.3975x; 1.3975x over previous
//
#include <hip/hip_runtime.h>
#include <math.h>

// ---------------- problem constants ----------------
#define BATCH 2
#define CCH   128
#define H1    96
#define W1    96
#define H2    48
#define W2    48
#define LP    2304   // H2*W2
#define K1    1152   // CCH*9   (3x3 im2col depth)
#define M2    2048   // CCH*16  (4x4 transpose-conv rows)

#define SZ_U   5308416u   // [2304][2304]
#define SZ_A   2654208u   // [1152][2304]
#define SZ_R   4718592u   // [2304][2048]
#define SZ_Z   4718592u   // [2048][2304]
#define SZ_Y   2359296u   // [2][128][96][96] (always both batches)

// ---------------- bilinear resize (exact jnp.linspace replication) ----------
__device__ __forceinline__ float lin_coord(int i) {
    if (i == 47) return 95.0f;
    return __fmul_rn(95.0f, __fdiv_rn((float)i, 47.0f));
}

__global__ void resize_masks(const float* __restrict__ mask,
                             const float* __restrict__ mask_all,
                             float* __restrict__ ms, float* __restrict__ ma) {
    int idx = blockIdx.x * 256 + threadIdx.x;
    if (idx >= BATCH * LP) return;
    int b = idx / LP, r = idx % LP;
    int i = r / W2, j = r % W2;
    float ys = lin_coord(i), xs = lin_coord(j);
    int y0 = (int)ys; int y1 = min(y0 + 1, 95);
    int x0 = (int)xs; int x1 = min(x0 + 1, 95);
    float wy = __fsub_rn(ys, (float)y0);
    float wx = __fsub_rn(xs, (float)x0);
    float wy1 = __fsub_rn(1.0f, wy), wx1 = __fsub_rn(1.0f, wx);
    const float* mb = mask + b * H1 * W1;
    float t0 = __fadd_rn(__fmul_rn(mb[y0*W1+x0], wy1), __fmul_rn(mb[y1*W1+x0], wy));
    float t1 = __fadd_rn(__fmul_rn(mb[y0*W1+x1], wy1), __fmul_rn(mb[y1*W1+x1], wy));
    ms[idx] = __fadd_rn(__fmul_rn(t0, wx1), __fmul_rn(t1, wx));
    const float* ab = mask_all + b * H1 * W1;
    t0 = __fadd_rn(__fmul_rn(ab[y0*W1+x0], wy1), __fmul_rn(ab[y1*W1+x0], wy));
    t1 = __fadd_rn(__fmul_rn(ab[y0*W1+x1], wy1), __fmul_rn(ab[y1*W1+x1], wy));
    ma[idx] = __fadd_rn(__fmul_rn(t0, wx1), __fmul_rn(t1, wx));
}

// mm[b,c] = 1 iff all 9 (zero-padded) 3x3 neighbors of mask_s are exactly 0.
__global__ void compute_mm(const float* __restrict__ ms, float* __restrict__ mm) {
    int idx = blockIdx.x * 256 + threadIdx.x;
    if (idx >= BATCH * LP) return;
    int b = idx / LP, r = idx % LP;
    int ci = r / W2, cj = r % W2;
    const float* m = ms + b * LP;
    bool any = false;
    #pragma unroll
    for (int di = -1; di <= 1; ++di)
        #pragma unroll
        for (int dj = -1; dj <= 1; ++dj) {
            int y = ci + di, x = cj + dj;
            if ((unsigned)y < H2 && (unsigned)x < W2)
                any = any || (m[y*W2 + x] > 0.0f);
        }
    mm[idx] = any ? 0.0f : 1.0f;
}

// A[z][k][p] = x2p[z, ch, i+dy, j+dx]  (pad 1)
__global__ void im2col_x2(const float* __restrict__ x2, float* __restrict__ A,
                          size_t sIn, size_t sOut) {
    int idx = blockIdx.x * 256 + threadIdx.x;
    int z = blockIdx.y;
    int k = idx / LP, p = idx % LP;
    int ch = k / 9, t = k % 9, dy = t / 3, dx = t % 3;
    int i = p / W2, j = p % W2;
    int y = i + dy - 1, x = j + dx - 1;
    float v = 0.0f;
    if ((unsigned)y < H2 && (unsigned)x < W2) v = x2[z*sIn + ch*LP + y*W2 + x];
    A[z*sOut + idx] = v;
}

// RwT[z][c][m] = x1p[z, ch, 2*ci+ky, 2*cj+kx] (pad 1), m = ch*16 + ky*4 + kx
__global__ void build_rwt(const float* __restrict__ x1, float* __restrict__ RwT,
                          size_t sIn, size_t sOut) {
    int idx = blockIdx.x * 256 + threadIdx.x;
    int z = blockIdx.y;
    int c = idx >> 11, m = idx & 2047;
    int ci = c / W2, cj = c % W2;
    int ch = m >> 4, kk = m & 15, ky = kk >> 2, kx = kk & 3;
    int y = 2*ci + ky - 1, x = 2*cj + kx - 1;
    float v = 0.0f;
    if ((unsigned)y < H1 && (unsigned)x < W1) v = x1[z*sIn + ch*H1*W1 + y*W1 + x];
    RwT[z*sOut + idx] = v;
}

// ---------------- fp32 SGEMM: C[m][n] = sum_k A[k][m] * B[k][n] ----------------
// 128x128 tile, BK=8, 4 waves (wave tile 64x64), 8x8 lane grid, 8x8/thread.
// SYM: compute upper-triangle blocks only, mirror-store the transpose.
template <bool SYM>
__global__ __launch_bounds__(256) void gemm_tn(const float* __restrict__ Ab,
                                               const float* __restrict__ Bb,
                                               float* __restrict__ Cb,
                                               int M, int N, int K,
                                               size_t sA, size_t sB, size_t sC) {
    const int bx = blockIdx.x, by = blockIdx.y, bz = blockIdx.z;
    if (SYM && by > bx) return;
    const float* A = Ab + (size_t)bz * sA;
    const float* B = Bb + (size_t)bz * sB;
    float*       C = Cb + (size_t)bz * sC;
    __shared__ float As[8][128];
    __shared__ float Bs[8][128];
    const int bm = by * 128, bn = bx * 128;
    const int tid = threadIdx.x;
    const int lane = tid & 63, w = tid >> 6;
    const int wm = w >> 1, wn = w & 1;           // 2x2 wave grid
    const int lr = lane >> 3, lcn = lane & 7;    // 8x8 lane grid
    const int row0 = wm * 64 + lr * 8;
    const int col0 = wn * 64 + lcn * 8;
    // staging: thread -> one float4 of A-tile and one of B-tile
    const int sr = tid >> 5, sc = (tid & 31) * 4;
    const float* Ap = A + (size_t)sr * M + bm + sc;
    const float* Bp = B + (size_t)sr * N + bn + sc;
    float4 pa = *(const float4*)Ap;
    float4 pb = *(const float4*)Bp;
    float acc[8][8] = {};
    const int nk = K >> 3;
    for (int ks = 0; ks < nk; ++ks) {
        *(float4*)&As[sr][sc] = pa;
        *(float4*)&Bs[sr][sc] = pb;
        __syncthreads();
        if (ks + 1 < nk) {
            pa = *(const float4*)(Ap + (size_t)(ks + 1) * 8 * M);
            pb = *(const float4*)(Bp + (size_t)(ks + 1) * 8 * N);
        }
        #pragma unroll
        for (int kk = 0; kk < 8; ++kk) {
            float4 a0 = *(const float4*)&As[kk][row0];
            float4 a1 = *(const float4*)&As[kk][row0 + 4];
            float4 b0 = *(const float4*)&Bs[kk][col0];
            float4 b1 = *(const float4*)&Bs[kk][col0 + 4];
            float af[8] = {a0.x, a0.y, a0.z, a0.w, a1.x, a1.y, a1.z, a1.w};
            float bf[8] = {b0.x, b0.y, b0.z, b0.w, b1.x, b1.y, b1.z, b1.w};
            #pragma unroll
            for (int i = 0; i < 8; ++i)
                #pragma unroll
                for (int j = 0; j < 8; ++j)
                    acc[i][j] = fmaf(af[i], bf[j], acc[i][j]);
        }
        __syncthreads();
    }
    float* Cp = C + (size_t)(bm + row0) * N + bn + col0;
    #pragma unroll
    for (int i = 0; i < 8; ++i) {
        *(float4*)&Cp[(size_t)i * N + 0] = make_float4(acc[i][0], acc[i][1], acc[i][2], acc[i][3]);
        *(float4*)&Cp[(size_t)i * N + 4] = make_float4(acc[i][4], acc[i][5], acc[i][6], acc[i][7]);
    }
    if (SYM && bx != by) {
        // mirror: thread's 8x8 block lands contiguously at (bn+col0, bm+row0)
        float* Cm = C + (size_t)(bn + col0) * N + bm + row0;
        #pragma unroll
        for (int j = 0; j < 8; ++j) {
            *(float4*)&Cm[(size_t)j * N + 0] = make_float4(acc[0][j], acc[1][j], acc[2][j], acc[3][j]);
            *(float4*)&Cm[(size_t)j * N + 4] = make_float4(acc[4][j], acc[5][j], acc[6][j], acc[7][j]);
        }
    }
}

// rcp[c] = 1 / max(sqrt(U[c][c]), 1e-4)
__global__ void diag_norm(const float* __restrict__ U, float* __restrict__ rcp,
                          size_t sU) {
    int c = blockIdx.x * 256 + threadIdx.x;
    int z = blockIdx.y;
    if (c >= LP) return;
    rcp[z*LP + c] = 1.0f / fmaxf(sqrtf(U[z*sU + (size_t)c * LP + c]), 1e-4f);
}

// Column softmax + masking + neighbor boost + clip, in place on U.
__global__ __launch_bounds__(256) void softmax_col(float* __restrict__ Ub,
                                                   const float* __restrict__ rcpn,
                                                   const float* __restrict__ mmb,
                                                   const float* __restrict__ mab,
                                                   size_t sU) {
    __shared__ float redM[4][64];
    __shared__ float redS[4][64];
    const int z = blockIdx.y;
    float* U = Ub + (size_t)z * sU;
    const float* rcp = rcpn + z * LP;
    const float* mm = mmb + z * LP;
    const float maF = mab[z * LP + blockIdx.x * 64 + (threadIdx.x & 63)];
    const int tx = threadIdx.x & 63, tg = threadIdx.x >> 6;
    const int p = blockIdx.x * 64 + tx;
    const int pi = p / W2, pj = p % W2;
    float mx = -INFINITY, sm = 0.0f;
    for (int c = tg; c < LP; c += 4) {
        float t = (((U[(size_t)c*LP + p] * rcp[c]) * mm[c]) * maF) * 10.0f;
        U[(size_t)c*LP + p] = t;   // cache logit for pass 2
        float nmx = fmaxf(mx, t);
        sm = sm * __expf(mx - nmx) + __expf(t - nmx);
        mx = nmx;
    }
    redM[tg][tx] = mx; redS[tg][tx] = sm;
    __syncthreads();
    float Mx = fmaxf(fmaxf(redM[0][tx], redM[1][tx]), fmaxf(redM[2][tx], redM[3][tx]));
    float S  = redS[0][tx]*__expf(redM[0][tx]-Mx) + redS[1][tx]*__expf(redM[1][tx]-Mx)
             + redS[2][tx]*__expf(redM[2][tx]-Mx) + redS[3][tx]*__expf(redM[3][tx]-Mx);
    float rS = 1.0f / S;
    for (int c = tg; c < LP; c += 4) {
        float t = U[(size_t)c*LP + p];
        float r = __expf(t - Mx) * rS;
        int ci = c / W2, cj = c - ci*W2;
        if (abs(ci - pi) + abs(cj - pj) == 1) r = r + r * 0.5f;
        r = (r * mm[c]) * maF;
        U[(size_t)c*LP + p] = fmaxf(r, 1e-8f);
    }
}

// y[z][ch][yy][xx] = 0.25 * sum over valid (ky,kx) of Z[(ch,ky,kx)][i*48+j]
__global__ void scatter_y(const float* __restrict__ Zb, float* __restrict__ yb,
                          size_t sZ, size_t sY) {
    int idx = blockIdx.x * 256 + threadIdx.x;
    int z = blockIdx.y;
    const float* Z = Zb + (size_t)z * sZ;
    int ch = idx / (H1*W1), r = idx % (H1*W1);
    int yy = r / W1, xx = r % W1;
    float s = 0.0f;
    #pragma unroll
    for (int ky = 0; ky < 4; ++ky) {
        int ny = yy + 1 - ky;
        if (ny & 1) continue;
        int i = ny >> 1;
        if ((unsigned)i >= H2) continue;
        #pragma unroll
        for (int kx = 0; kx < 4; ++kx) {
            int nx = xx + 1 - kx;
            if (nx & 1) continue;
            int j = nx >> 1;
            if ((unsigned)j >= W2) continue;
            s += Z[(size_t)(ch*16 + ky*4 + kx) * LP + i*W2 + j];
        }
    }
    yb[(size_t)z * sY + idx] = s * 0.25f;
}

// 4 dilated 3x3 convs (dilation 1,2,4,8; "same"), +bias, relu, concat.
__global__ __launch_bounds__(256) void dilated_conv(const float* __restrict__ y,
                                                    const float* __restrict__ w,
                                                    const float* __restrict__ bias,
                                                    float* __restrict__ out) {
    int bid = blockIdx.x;                 // b*4*36 + g*36 + tile
    int tile = bid % 36; int g = (bid / 36) % 4; int b = bid / 144;
    int yy = (tile / 6) * 16 + (threadIdx.x >> 4);
    int xx = (tile % 6) * 16 + (threadIdx.x & 15);
    int rr = 1 << g;                      // RATES = 1,2,4,8
    const float* yb = y + (size_t)b * CCH * H1 * W1;
    const float* wg = w + g * 16 * CCH * 9;
    float acc[16] = {};
    for (int ic = 0; ic < CCH; ++ic) {
        const float* yc = yb + ic * H1 * W1;
        #pragma unroll
        for (int t = 0; t < 9; ++t) {
            int sy = yy + rr * (t / 3 - 1), sx = xx + rr * (t % 3 - 1);
            float v = 0.0f;
            if ((unsigned)sy < H1 && (unsigned)sx < W1) v = yc[sy*W1 + sx];
            #pragma unroll
            for (int oc = 0; oc < 16; ++oc)
                acc[oc] = fmaf(v, wg[(oc*CCH + ic)*9 + t], acc[oc]);
        }
    }
    #pragma unroll
    for (int oc = 0; oc < 16; ++oc) {
        float o = fmaxf(acc[oc] + bias[g*16 + oc], 0.0f);
        out[(size_t)((b*64 + g*16 + oc) * (H1*W1)) + yy*W1 + xx] = o;
    }
}

extern "C" void kernel_launch(void* const* d_in, const int* in_sizes, int n_in,
                              void* d_out, int out_size, void* d_ws, size_t ws_size,
                              hipStream_t stream) {
    const float* x1       = (const float*)d_in[0];
    const float* x2       = (const float*)d_in[1];
    const float* mask     = (const float*)d_in[2];
    const float* mask_all = (const float*)d_in[3];
    const float* conv_w   = (const float*)d_in[4];
    const float* conv_b   = (const float*)d_in[5];

    // dual-batch layout if workspace allows, else per-batch reuse
    const size_t smallTot = 4 * 4608ull;
    const size_t dualNeed  = (2ull*SZ_U + 2ull*SZ_A + 2ull*SZ_R + 2ull*SZ_Z + SZ_Y + smallTot) * 4;
    const size_t seqNeed   = (1ull*SZ_U + 1ull*SZ_A + 1ull*SZ_R + 1ull*SZ_Z + SZ_Y + smallTot) * 4;
    if (ws_size < seqNeed) return;  // insufficient scratch -> fail loudly
    const int NZ = (ws_size >= dualNeed) ? 2 : 1;

    float* ws  = (float*)d_ws;
    float* U   = ws;
    float* A   = U + (size_t)NZ * SZ_U;
    float* RWT = A + (size_t)NZ * SZ_A;
    float* Z   = RWT + (size_t)NZ * SZ_R;
    float* Y   = Z + (size_t)NZ * SZ_Z;
    float* MS  = Y + SZ_Y;
    float* MA  = MS + 4608;
    float* MM  = MA + 4608;
    float* RCP = MM + 4608;

    resize_masks<<<18, 256, 0, stream>>>(mask, mask_all, MS, MA);
    compute_mm<<<18, 256, 0, stream>>>(MS, MM);

    const size_t sX2 = (size_t)CCH * LP;          // x2 batch stride
    const size_t sX1 = (size_t)CCH * H1 * W1;     // x1 batch stride
    const size_t sYb = (size_t)CCH * H1 * W1;     // Y batch stride

    const int nIter = (NZ == 2) ? 1 : 2;
    for (int it = 0; it < nIter; ++it) {
        const int b0 = (NZ == 2) ? 0 : it;
        const size_t zU = (NZ == 2) ? SZ_U : 0, zA = (NZ == 2) ? SZ_A : 0;
        const size_t zR = (NZ == 2) ? SZ_R : 0, zZ = (NZ == 2) ? SZ_Z : 0;
        // masks are always [2][...]: in seq mode offset by b0, stride unused (z=0)
        im2col_x2<<<dim3((K1 * LP) / 256, NZ), 256, 0, stream>>>(
            x2 + (size_t)b0 * sX2, A, sX2, zA);
        gemm_tn<true><<<dim3(18, 18, NZ), 256, 0, stream>>>(
            A, A, U, LP, LP, K1, zA, zA, zU);
        diag_norm<<<dim3(9, NZ), 256, 0, stream>>>(U, RCP + (NZ==2?0:(size_t)b0*LP) - (size_t)0, zU);
        // note: diag_norm writes rcp[z*LP + c]; in seq mode z==0 so offset manually:
        if (NZ == 1) {
            // re-run pointer-corrected softmax below uses RCP + b0*LP; diag wrote RCP+0.
        }
        softmax_col<<<dim3(36, NZ), 256, 0, stream>>>(
            U, (NZ==2) ? RCP : RCP - 0, (NZ==2) ? MM : MM + (size_t)b0*LP,
            (NZ==2) ? MA : MA + (size_t)b0*LP, zU);
        build_rwt<<<dim3((LP * M2) / 256, NZ), 256, 0, stream>>>(
            x1 + (size_t)b0 * sX1, RWT, sX1, zR);
        gemm_tn<false><<<dim3(18, 16, NZ), 256, 0, stream>>>(
            RWT, U, Z, M2, LP, LP, zR, zU, zZ);
        scatter_y<<<dim3((CCH * H1 * W1) / 256, NZ), 256, 0, stream>>>(
            Z, Y + (size_t)b0 * sYb, zZ, sYb);
    }
    dilated_conv<<<288, 256, 0, stream>>>(Y, conv_w, conv_b, (float*)d_out);
}

// Round 7
// 656.150 us; speedup vs baseline: 3.2623x; 2.3344x over previous
//
#include <hip/hip_runtime.h>
#include <math.h>

// ---------------- problem constants ----------------
#define BATCH 2
#define CCH   128
#define H1    96
#define W1    96
#define H2    48
#define W2    48
#define LP    2304   // H2*W2
#define K1    1152   // CCH*9
#define M2    2048   // CCH*16

typedef __attribute__((ext_vector_type(8))) short short8;
typedef __attribute__((ext_vector_type(4))) float f32x4;
typedef __attribute__((ext_vector_type(4))) short short4v;

// bf16 helpers (RN-even)
__device__ __forceinline__ unsigned short f2bf(float x) {
    unsigned u = __float_as_uint(x);
    return (unsigned short)((u + 0x7fffu + ((u >> 16) & 1u)) >> 16);
}
__device__ __forceinline__ float bf2f(unsigned short h) {
    return __uint_as_float(((unsigned)h) << 16);
}

// ---------------- bilinear resize (exact jnp.linspace replication) ----------
__device__ __forceinline__ float lin_coord(int i) {
    if (i == 47) return 95.0f;
    return __fmul_rn(95.0f, __fdiv_rn((float)i, 47.0f));
}

__global__ void resize_masks(const float* __restrict__ mask,
                             const float* __restrict__ mask_all,
                             float* __restrict__ ms, float* __restrict__ ma) {
    int idx = blockIdx.x * 256 + threadIdx.x;
    if (idx >= BATCH * LP) return;
    int b = idx / LP, r = idx % LP;
    int i = r / W2, j = r % W2;
    float ys = lin_coord(i), xs = lin_coord(j);
    int y0 = (int)ys; int y1 = min(y0 + 1, 95);
    int x0 = (int)xs; int x1 = min(x0 + 1, 95);
    float wy = __fsub_rn(ys, (float)y0);
    float wx = __fsub_rn(xs, (float)x0);
    float wy1 = __fsub_rn(1.0f, wy), wx1 = __fsub_rn(1.0f, wx);
    const float* mb = mask + b * H1 * W1;
    float t0 = __fadd_rn(__fmul_rn(mb[y0*W1+x0], wy1), __fmul_rn(mb[y1*W1+x0], wy));
    float t1 = __fadd_rn(__fmul_rn(mb[y0*W1+x1], wy1), __fmul_rn(mb[y1*W1+x1], wy));
    ms[idx] = __fadd_rn(__fmul_rn(t0, wx1), __fmul_rn(t1, wx));
    const float* ab = mask_all + b * H1 * W1;
    t0 = __fadd_rn(__fmul_rn(ab[y0*W1+x0], wy1), __fmul_rn(ab[y1*W1+x0], wy));
    t1 = __fadd_rn(__fmul_rn(ab[y0*W1+x1], wy1), __fmul_rn(ab[y1*W1+x1], wy));
    ma[idx] = __fadd_rn(__fmul_rn(t0, wx1), __fmul_rn(t1, wx));
}

__global__ void compute_mm(const float* __restrict__ ms, float* __restrict__ mm) {
    int idx = blockIdx.x * 256 + threadIdx.x;
    if (idx >= BATCH * LP) return;
    int b = idx / LP, r = idx % LP;
    int ci = r / W2, cj = r % W2;
    const float* m = ms + b * LP;
    bool any = false;
    #pragma unroll
    for (int di = -1; di <= 1; ++di)
        #pragma unroll
        for (int dj = -1; dj <= 1; ++dj) {
            int y = ci + di, x = cj + dj;
            if ((unsigned)y < H2 && (unsigned)x < W2)
                any = any || (m[y*W2 + x] > 0.0f);
        }
    mm[idx] = any ? 0.0f : 1.0f;
}

// im2col of x2 into TRIPLE-split bf16 padded tiles: [by][kt][r=128][40 shorts]
__global__ void im2col_split3(const float* __restrict__ x2,
                              short* __restrict__ A0, short* __restrict__ A1,
                              short* __restrict__ A2,
                              size_t sIn, size_t sOut) {
    int idx = blockIdx.x * 256 + threadIdx.x;      // p*K1 + k
    int z = blockIdx.y;
    int p = idx / K1, k = idx - p * K1;
    int ch = k / 9, t = k - ch * 9, dy = t / 3, dx = t - dy * 3;
    int i = p / W2, j = p - i * W2;
    int y = i + dy - 1, x = j + dx - 1;
    float v = 0.0f;
    if ((unsigned)y < H2 && (unsigned)x < W2) v = x2[z*sIn + ch*LP + y*W2 + x];
    unsigned short h0 = f2bf(v);
    float r1 = v - bf2f(h0);
    unsigned short h1 = f2bf(r1);
    unsigned short h2 = f2bf(r1 - bf2f(h1));
    size_t off = ((size_t)((p >> 7) * 36 + (k >> 5)) * 128 + (p & 127)) * 40 + (k & 31);
    A0[z*sOut + off] = (short)h0;
    A1[z*sOut + off] = (short)h1;
    A2[z*sOut + off] = (short)h2;
}

// raw_w rows into 2-split bf16 padded tiles: [mby][ckt][r=128][40 shorts]
__global__ void rwt_split(const float* __restrict__ x1,
                          short* __restrict__ Rh, short* __restrict__ Rl,
                          size_t sIn, size_t sOut) {
    int idx = blockIdx.x * 256 + threadIdx.x;      // m*LP + c
    int z = blockIdx.y;
    int m = idx / LP, c = idx - m * LP;
    int ci = c / W2, cj = c - ci * W2;
    int ch = m >> 4, kk = m & 15, ky = kk >> 2, kx = kk & 3;
    int y = 2*ci + ky - 1, x = 2*cj + kx - 1;
    float v = 0.0f;
    if ((unsigned)y < H1 && (unsigned)x < W1) v = x1[z*sIn + (size_t)ch*H1*W1 + y*W1 + x];
    unsigned short h = f2bf(v);
    unsigned short l = f2bf(v - bf2f(h));
    size_t off = ((size_t)((m >> 7) * 72 + (c >> 5)) * 128 + (m & 127)) * 40 + (c & 31);
    Rh[z*sOut + off] = (short)h;
    Rl[z*sOut + off] = (short)l;
}

// ---------------- S-split bf16 MFMA GEMM ----------------
// C[m][n] = sum_k A[m][k]*B[n][k], A = sum A_s, B = sum B_s; products i+j<S.
// Tiles: [tile][kt][128][40 shorts]. 4 waves (2x2), wave 64x64, 16x16x32 frags.
template <int S>
__global__ __launch_bounds__(256) void gemm_mfma_split(
    const short* __restrict__ A0, const short* __restrict__ A1,
    const short* __restrict__ A2,
    const short* __restrict__ B0, const short* __restrict__ B1,
    const short* __restrict__ B2,
    float* __restrict__ Cb, const int KT, const int N,
    const size_t sA, const size_t sB, const size_t sC)
{
    __shared__ f32x4 lds4[2 * S * 640];            // 2*S*10240 bytes
    char* lds = (char*)lds4;
    const int bx = blockIdx.x, by = blockIdx.y, bz = blockIdx.z;
    const int tid = threadIdx.x, lane = tid & 63, w = tid >> 6;
    const int wm = w >> 1, wn = w & 1;
    const size_t tA = (size_t)bz * sA + (size_t)by * KT * 5120;
    const size_t tB = (size_t)bz * sB + (size_t)bx * KT * 5120;

    // staging assignment: arrays 0..S-1 = A splits, S..2S-1 = B splits
    const short* s1; char* d1;
    const short* s2 = nullptr; char* d2 = nullptr;
    if constexpr (S == 2) {
        s1 = (w == 0 ? A0 : w == 1 ? A1 : w == 2 ? B0 : B1) + ((w < 2) ? tA : tB);
        d1 = lds + w * 10240;
    } else {
        s1 = (w == 0 ? A0 : w == 1 ? A1 : w == 2 ? A2 : B0) + ((w < 3) ? tA : tB);
        d1 = lds + w * 10240;
        if (w < 2) { s2 = (w == 0 ? B1 : B2) + tB; d2 = lds + (4 + w) * 10240; }
    }

    f32x4 acc[4][4];
    #pragma unroll
    for (int i = 0; i < 4; ++i)
        #pragma unroll
        for (int j = 0; j < 4; ++j) acc[i][j] = (f32x4){0.f, 0.f, 0.f, 0.f};

    const int fr = lane & 15;
    const int fkb = (lane >> 4) * 16;

    for (int kt = 0; kt < KT; ++kt) {
        const char* g1 = (const char*)(s1 + (size_t)kt * 5120);
        #pragma unroll
        for (int u = 0; u < 10; ++u)
            __builtin_amdgcn_global_load_lds(
                (const __attribute__((address_space(1))) unsigned int*)(g1 + u*1024 + lane*16),
                (__attribute__((address_space(3))) unsigned int*)(d1 + u*1024),
                16, 0, 0);
        if constexpr (S == 3) {
            if (w < 2) {
                const char* g2 = (const char*)(s2 + (size_t)kt * 5120);
                #pragma unroll
                for (int u = 0; u < 10; ++u)
                    __builtin_amdgcn_global_load_lds(
                        (const __attribute__((address_space(1))) unsigned int*)(g2 + u*1024 + lane*16),
                        (__attribute__((address_space(3))) unsigned int*)(d2 + u*1024),
                        16, 0, 0);
            }
        }
        __syncthreads();

        short8 bf[S][4];
        #pragma unroll
        for (int s = 0; s < S; ++s)
            #pragma unroll
            for (int ni = 0; ni < 4; ++ni) {
                const int r = wn*64 + ni*16 + fr;
                bf[s][ni] = *(const short8*)(lds + (S + s)*10240 + r*80 + fkb);
            }
        #pragma unroll
        for (int mi = 0; mi < 4; ++mi) {
            const int r = wm*64 + mi*16 + fr;
            short8 af[S];
            #pragma unroll
            for (int s = 0; s < S; ++s)
                af[s] = *(const short8*)(lds + s*10240 + r*80 + fkb);
            #pragma unroll
            for (int ni = 0; ni < 4; ++ni) {
                acc[mi][ni] = __builtin_amdgcn_mfma_f32_16x16x32_bf16(af[0], bf[0][ni], acc[mi][ni], 0, 0, 0);
                acc[mi][ni] = __builtin_amdgcn_mfma_f32_16x16x32_bf16(af[0], bf[1][ni], acc[mi][ni], 0, 0, 0);
                acc[mi][ni] = __builtin_amdgcn_mfma_f32_16x16x32_bf16(af[1], bf[0][ni], acc[mi][ni], 0, 0, 0);
                if constexpr (S == 3) {
                    acc[mi][ni] = __builtin_amdgcn_mfma_f32_16x16x32_bf16(af[0], bf[2][ni], acc[mi][ni], 0, 0, 0);
                    acc[mi][ni] = __builtin_amdgcn_mfma_f32_16x16x32_bf16(af[1], bf[1][ni], acc[mi][ni], 0, 0, 0);
                    acc[mi][ni] = __builtin_amdgcn_mfma_f32_16x16x32_bf16(af[2], bf[0][ni], acc[mi][ni], 0, 0, 0);
                }
            }
        }
        __syncthreads();
    }
    // epilogue: D col=lane&15, row=(lane>>4)*4+reg  [verified m89 mapping]
    float* C = Cb + (size_t)bz * sC;
    const int cr = (lane >> 4) * 4, cc = lane & 15;
    const int row0 = by*128 + wm*64, col0 = bx*128 + wn*64;
    #pragma unroll
    for (int mi = 0; mi < 4; ++mi)
        #pragma unroll
        for (int ni = 0; ni < 4; ++ni) {
            float* cp = C + (size_t)(row0 + mi*16 + cr) * N + col0 + ni*16 + cc;
            #pragma unroll
            for (int rg = 0; rg < 4; ++rg)
                cp[(size_t)rg * N] = acc[mi][ni][rg];
        }
}

// rcp[z][c] = 1 / max(sqrt(U[c][c]), 1e-4)
__global__ void diag_rcp(const float* __restrict__ U, float* __restrict__ rcp,
                         size_t sU) {
    int c = blockIdx.x * 256 + threadIdx.x;
    int z = blockIdx.y;
    if (c >= LP) return;
    rcp[z*LP + c] = 1.0f / fmaxf(sqrtf(U[(size_t)z*sU + (size_t)c * (LP + 1)]), 1e-4f);
}

// Row softmax over U[p][*] fused with masking, boost, clip, bf16 2-split.
// One wave per row p; writes V tiles [pby][ckt][r][40].
__global__ __launch_bounds__(256) void softmax_split(
    const float* __restrict__ Ub, const float* __restrict__ rcpb,
    const float* __restrict__ mmb, const float* __restrict__ mab,
    short* __restrict__ Vhi, short* __restrict__ Vlo,
    size_t sU, size_t sV)
{
    const int z = blockIdx.y;
    const int wid = threadIdx.x >> 6, lane = threadIdx.x & 63;
    const int p = blockIdx.x * 4 + wid;
    const float* U = Ub + (size_t)z * sU + (size_t)p * LP;
    const float* rcp = rcpb + z * LP;
    const float* mm = mmb + (size_t)z * LP;        // z-offset (round-3 bug fix)
    const float maP = mab[(size_t)z * LP + p];     // z-offset (round-3 bug fix)
    const float maS = maP * 10.0f;
    float t[9][4], mv[9][4];
    float mx = -INFINITY;
    #pragma unroll
    for (int i = 0; i < 9; ++i) {
        const int c = i * 256 + lane * 4;
        float4 u4 = *(const float4*)(U + c);
        float4 r4 = *(const float4*)(rcp + c);
        float4 m4 = *(const float4*)(mm + c);
        t[i][0] = u4.x * r4.x * m4.x * maS;  mv[i][0] = m4.x;
        t[i][1] = u4.y * r4.y * m4.y * maS;  mv[i][1] = m4.y;
        t[i][2] = u4.z * r4.z * m4.z * maS;  mv[i][2] = m4.z;
        t[i][3] = u4.w * r4.w * m4.w * maS;  mv[i][3] = m4.w;
        #pragma unroll
        for (int jj = 0; jj < 4; ++jj) mx = fmaxf(mx, t[i][jj]);
    }
    #pragma unroll
    for (int off = 32; off > 0; off >>= 1) mx = fmaxf(mx, __shfl_xor(mx, off, 64));
    float sm = 0.0f;
    #pragma unroll
    for (int i = 0; i < 9; ++i)
        #pragma unroll
        for (int jj = 0; jj < 4; ++jj) sm += __expf(t[i][jj] - mx);
    #pragma unroll
    for (int off = 32; off > 0; off >>= 1) sm += __shfl_xor(sm, off, 64);
    const float rS = 1.0f / sm;
    const int pi = p / W2, pj = p - pi * W2;
    const int pby = p >> 7, pr = p & 127;
    #pragma unroll
    for (int i = 0; i < 9; ++i) {
        const int c = i * 256 + lane * 4;
        short4v h4, l4;
        #pragma unroll
        for (int jj = 0; jj < 4; ++jj) {
            int cc = c + jj;
            float r = __expf(t[i][jj] - mx) * rS;
            int ci = cc / W2, cj = cc - ci * W2;
            if (abs(ci - pi) + abs(cj - pj) == 1) r = r + r * 0.5f;
            r = (r * mv[i][jj]) * maP;
            r = fmaxf(r, 1e-8f);
            unsigned short h = f2bf(r);
            unsigned short l = f2bf(r - bf2f(h));
            h4[jj] = (short)h; l4[jj] = (short)l;
        }
        size_t voff = ((size_t)(pby * 72 + (c >> 5)) * 128 + pr) * 40 + (c & 31);
        *(short4v*)(Vhi + (size_t)z * sV + voff) = h4;
        *(short4v*)(Vlo + (size_t)z * sV + voff) = l4;
    }
}

// y[z][ch][yy][xx] = 0.25 * sum over valid (ky,kx) of Z[(ch,ky,kx)][i*48+j]
__global__ void scatter_y(const float* __restrict__ Zb, float* __restrict__ yb,
                          size_t sZ, size_t sY) {
    int idx = blockIdx.x * 256 + threadIdx.x;
    int z = blockIdx.y;
    const float* Z = Zb + (size_t)z * sZ;
    int ch = idx / (H1*W1), r = idx % (H1*W1);
    int yy = r / W1, xx = r % W1;
    float s = 0.0f;
    #pragma unroll
    for (int ky = 0; ky < 4; ++ky) {
        int ny = yy + 1 - ky;
        if (ny & 1) continue;
        int i = ny >> 1;
        if ((unsigned)i >= H2) continue;
        #pragma unroll
        for (int kx = 0; kx < 4; ++kx) {
            int nx = xx + 1 - kx;
            if (nx & 1) continue;
            int j = nx >> 1;
            if ((unsigned)j >= W2) continue;
            s += Z[(size_t)(ch*16 + ky*4 + kx) * LP + i*W2 + j];
        }
    }
    yb[(size_t)z * sY + idx] = s * 0.25f;
}

// 4 dilated 3x3 convs (dilation 1,2,4,8; "same"), +bias, relu, concat.
__global__ __launch_bounds__(256) void dilated_conv(const float* __restrict__ y,
                                                    const float* __restrict__ w,
                                                    const float* __restrict__ bias,
                                                    float* __restrict__ out) {
    int bid = blockIdx.x;                 // b*4*36 + g*36 + tile
    int tile = bid % 36; int g = (bid / 36) % 4; int b = bid / 144;
    int yy = (tile / 6) * 16 + (threadIdx.x >> 4);
    int xx = (tile % 6) * 16 + (threadIdx.x & 15);
    int rr = 1 << g;
    const float* yb = y + (size_t)b * CCH * H1 * W1;
    const float* wg = w + g * 16 * CCH * 9;
    float acc[16] = {};
    for (int ic = 0; ic < CCH; ++ic) {
        const float* yc = yb + ic * H1 * W1;
        #pragma unroll
        for (int t = 0; t < 9; ++t) {
            int sy = yy + rr * (t / 3 - 1), sx = xx + rr * (t % 3 - 1);
            float v = 0.0f;
            if ((unsigned)sy < H1 && (unsigned)sx < W1) v = yc[sy*W1 + sx];
            #pragma unroll
            for (int oc = 0; oc < 16; ++oc)
                acc[oc] = fmaf(v, wg[(oc*CCH + ic)*9 + t], acc[oc]);
        }
    }
    #pragma unroll
    for (int oc = 0; oc < 16; ++oc) {
        float o = fmaxf(acc[oc] + bias[g*16 + oc], 0.0f);
        out[(size_t)((b*64 + g*16 + oc) * (H1*W1)) + yy*W1 + xx] = o;
    }
}

extern "C" void kernel_launch(void* const* d_in, const int* in_sizes, int n_in,
                              void* d_out, int out_size, void* d_ws, size_t ws_size,
                              hipStream_t stream) {
    const float* x1       = (const float*)d_in[0];
    const float* x2       = (const float*)d_in[1];
    const float* mask     = (const float*)d_in[2];
    const float* mask_all = (const float*)d_in[3];
    const float* conv_w   = (const float*)d_in[4];
    const float* conv_b   = (const float*)d_in[5];

    // per-batch element counts
    const size_t EA = 3317760;   // shorts: 18*36*128*40
    const size_t ER = 5898240;   // shorts: 16*72*128*40
    const size_t EV = 6635520;   // shorts: 18*72*128*40
    const size_t FU = 5308416;   // floats: 2304*2304
    const size_t FZ = 4718592;   // floats: 2048*2304
    const size_t FY = 2359296;   // floats: both batches of Y

    struct Offs { size_t A0, A1, A2, U, Rhi, Rlo, Z, Vhi, Vlo, Y, MS, MA, MM, RCP, need; };
    auto mk = [&](int NZ) {
        Offs o;
        o.A0 = 0;
        o.A1 = o.A0 + (size_t)NZ * EA * 2;
        o.A2 = o.A1 + (size_t)NZ * EA * 2;
        o.U  = o.A2 + (size_t)NZ * EA * 2;
        size_t endA = o.U + (size_t)NZ * FU * 4;
        o.Rhi = 0;                               // reuses A/U region (dead by then)
        o.Rlo = o.Rhi + (size_t)NZ * ER * 2;
        o.Z   = o.Rlo + (size_t)NZ * ER * 2;
        size_t endR = o.Z + (size_t)NZ * FZ * 4;
        size_t r1 = endA > endR ? endA : endR;
        o.Vhi = r1;
        o.Vlo = o.Vhi + (size_t)NZ * EV * 2;
        o.Y   = o.Vlo + (size_t)NZ * EV * 2;
        o.MS  = o.Y + FY * 4;
        o.MA  = o.MS + 4608 * 4;
        o.MM  = o.MA + 4608 * 4;
        o.RCP = o.MM + 4608 * 4;
        o.need = o.RCP + 4608 * 4;
        return o;
    };
    Offs o2 = mk(2), o1 = mk(1);
    if (ws_size < o1.need) return;               // fail loudly
    const int NZ = (ws_size >= o2.need) ? 2 : 1;
    Offs o = (NZ == 2) ? o2 : o1;

    char* base = (char*)d_ws;
    short* A0  = (short*)(base + o.A0);
    short* A1  = (short*)(base + o.A1);
    short* A2  = (short*)(base + o.A2);
    float* U   = (float*)(base + o.U);
    short* Rhi = (short*)(base + o.Rhi);
    short* Rlo = (short*)(base + o.Rlo);
    float* Z   = (float*)(base + o.Z);
    short* Vhi = (short*)(base + o.Vhi);
    short* Vlo = (short*)(base + o.Vlo);
    float* Y   = (float*)(base + o.Y);
    float* MS  = (float*)(base + o.MS);
    float* MA  = (float*)(base + o.MA);
    float* MM  = (float*)(base + o.MM);
    float* RCP = (float*)(base + o.RCP);

    resize_masks<<<18, 256, 0, stream>>>(mask, mask_all, MS, MA);
    compute_mm<<<18, 256, 0, stream>>>(MS, MM);

    const size_t sX2 = (size_t)CCH * LP;
    const size_t sX1 = (size_t)CCH * H1 * W1;
    const size_t sYb = (size_t)CCH * H1 * W1;

    const int nIter = (NZ == 2) ? 1 : 2;
    for (int it = 0; it < nIter; ++it) {
        const int b0 = (NZ == 2) ? 0 : it;
        im2col_split3<<<dim3(10368, NZ), 256, 0, stream>>>(
            x2 + (size_t)b0 * sX2, A0, A1, A2, sX2, EA);
        gemm_mfma_split<3><<<dim3(18, 18, NZ), 256, 0, stream>>>(
            A0, A1, A2, A0, A1, A2, U, 36, LP, EA, EA, FU);
        diag_rcp<<<dim3(9, NZ), 256, 0, stream>>>(U, RCP, FU);
        softmax_split<<<dim3(576, NZ), 256, 0, stream>>>(
            U, RCP, MM + (size_t)b0 * LP, MA + (size_t)b0 * LP, Vhi, Vlo, FU, EV);
        rwt_split<<<dim3(18432, NZ), 256, 0, stream>>>(
            x1 + (size_t)b0 * sX1, Rhi, Rlo, sX1, ER);
        gemm_mfma_split<2><<<dim3(18, 16, NZ), 256, 0, stream>>>(
            Rhi, Rlo, nullptr, Vhi, Vlo, nullptr, Z, 72, LP, ER, EV, FZ);
        scatter_y<<<dim3(4608, NZ), 256, 0, stream>>>(
            Z, Y + (size_t)b0 * sYb, FZ, sYb);
    }
    dilated_conv<<<288, 256, 0, stream>>>(Y, conv_w, conv_b, (float*)d_out);
}

// Round 8
// 575.202 us; speedup vs baseline: 3.7214x; 1.1407x over previous
//
#include <hip/hip_runtime.h>
#include <math.h>

// ---------------- problem constants ----------------
#define BATCH 2
#define CCH   128
#define H1    96
#define W1    96
#define H2    48
#define W2    48
#define LP    2304   // H2*W2
#define K1    1152   // CCH*9
#define M2    2048   // CCH*16

typedef __attribute__((ext_vector_type(8))) short short8;
typedef __attribute__((ext_vector_type(4))) float f32x4;
typedef __attribute__((ext_vector_type(4))) short short4v;

// bf16 helpers (RN-even)
__device__ __forceinline__ unsigned short f2bf(float x) {
    unsigned u = __float_as_uint(x);
    return (unsigned short)((u + 0x7fffu + ((u >> 16) & 1u)) >> 16);
}
__device__ __forceinline__ float bf2f(unsigned short h) {
    return __uint_as_float(((unsigned)h) << 16);
}

// ---------------- bilinear resize (exact jnp.linspace replication) ----------
__device__ __forceinline__ float lin_coord(int i) {
    if (i == 47) return 95.0f;
    return __fmul_rn(95.0f, __fdiv_rn((float)i, 47.0f));
}

__global__ void resize_masks(const float* __restrict__ mask,
                             const float* __restrict__ mask_all,
                             float* __restrict__ ms, float* __restrict__ ma) {
    int idx = blockIdx.x * 256 + threadIdx.x;
    if (idx >= BATCH * LP) return;
    int b = idx / LP, r = idx % LP;
    int i = r / W2, j = r % W2;
    float ys = lin_coord(i), xs = lin_coord(j);
    int y0 = (int)ys; int y1 = min(y0 + 1, 95);
    int x0 = (int)xs; int x1 = min(x0 + 1, 95);
    float wy = __fsub_rn(ys, (float)y0);
    float wx = __fsub_rn(xs, (float)x0);
    float wy1 = __fsub_rn(1.0f, wy), wx1 = __fsub_rn(1.0f, wx);
    const float* mb = mask + b * H1 * W1;
    float t0 = __fadd_rn(__fmul_rn(mb[y0*W1+x0], wy1), __fmul_rn(mb[y1*W1+x0], wy));
    float t1 = __fadd_rn(__fmul_rn(mb[y0*W1+x1], wy1), __fmul_rn(mb[y1*W1+x1], wy));
    ms[idx] = __fadd_rn(__fmul_rn(t0, wx1), __fmul_rn(t1, wx));
    const float* ab = mask_all + b * H1 * W1;
    t0 = __fadd_rn(__fmul_rn(ab[y0*W1+x0], wy1), __fmul_rn(ab[y1*W1+x0], wy));
    t1 = __fadd_rn(__fmul_rn(ab[y0*W1+x1], wy1), __fmul_rn(ab[y1*W1+x1], wy));
    ma[idx] = __fadd_rn(__fmul_rn(t0, wx1), __fmul_rn(t1, wx));
}

__global__ void compute_mm(const float* __restrict__ ms, float* __restrict__ mm) {
    int idx = blockIdx.x * 256 + threadIdx.x;
    if (idx >= BATCH * LP) return;
    int b = idx / LP, r = idx % LP;
    int ci = r / W2, cj = r % W2;
    const float* m = ms + b * LP;
    bool any = false;
    #pragma unroll
    for (int di = -1; di <= 1; ++di)
        #pragma unroll
        for (int dj = -1; dj <= 1; ++dj) {
            int y = ci + di, x = cj + dj;
            if ((unsigned)y < H2 && (unsigned)x < W2)
                any = any || (m[y*W2 + x] > 0.0f);
        }
    mm[idx] = any ? 0.0f : 1.0f;
}

// im2col of x2 into TRIPLE-split bf16 padded tiles: [by][kt][r=128][40 shorts]
__global__ void im2col_split3(const float* __restrict__ x2,
                              short* __restrict__ A0, short* __restrict__ A1,
                              short* __restrict__ A2,
                              size_t sIn, size_t sOut) {
    int idx = blockIdx.x * 256 + threadIdx.x;      // p*K1 + k
    int z = blockIdx.y;
    int p = idx / K1, k = idx - p * K1;
    int ch = k / 9, t = k - ch * 9, dy = t / 3, dx = t - dy * 3;
    int i = p / W2, j = p - i * W2;
    int y = i + dy - 1, x = j + dx - 1;
    float v = 0.0f;
    if ((unsigned)y < H2 && (unsigned)x < W2) v = x2[z*sIn + ch*LP + y*W2 + x];
    unsigned short h0 = f2bf(v);
    float r1 = v - bf2f(h0);
    unsigned short h1 = f2bf(r1);
    unsigned short h2 = f2bf(r1 - bf2f(h1));
    size_t off = ((size_t)((p >> 7) * 36 + (k >> 5)) * 128 + (p & 127)) * 40 + (k & 31);
    A0[z*sOut + off] = (short)h0;
    A1[z*sOut + off] = (short)h1;
    A2[z*sOut + off] = (short)h2;
}

// raw_w rows into 2-split bf16 padded tiles: [mby][ckt][r=128][40 shorts]
__global__ void rwt_split(const float* __restrict__ x1,
                          short* __restrict__ Rh, short* __restrict__ Rl,
                          size_t sIn, size_t sOut) {
    int idx = blockIdx.x * 256 + threadIdx.x;      // m*LP + c
    int z = blockIdx.y;
    int m = idx / LP, c = idx - m * LP;
    int ci = c / W2, cj = c - ci * W2;
    int ch = m >> 4, kk = m & 15, ky = kk >> 2, kx = kk & 3;
    int y = 2*ci + ky - 1, x = 2*cj + kx - 1;
    float v = 0.0f;
    if ((unsigned)y < H1 && (unsigned)x < W1) v = x1[z*sIn + (size_t)ch*H1*W1 + y*W1 + x];
    unsigned short h = f2bf(v);
    unsigned short l = f2bf(v - bf2f(h));
    size_t off = ((size_t)((m >> 7) * 72 + (c >> 5)) * 128 + (m & 127)) * 40 + (c & 31);
    Rh[z*sOut + off] = (short)h;
    Rl[z*sOut + off] = (short)l;
}

// ---------------- S-split bf16 MFMA GEMM ----------------
// C[m][n] = sum_k A[m][k]*B[n][k], A = sum A_s, B = sum B_s; products i+j<S.
// Tiles: [tile][kt][128][40 shorts]. 4 waves (2x2), wave 64x64, 16x16x32 frags.
template <int S>
__global__ __launch_bounds__(256) void gemm_mfma_split(
    const short* __restrict__ A0, const short* __restrict__ A1,
    const short* __restrict__ A2,
    const short* __restrict__ B0, const short* __restrict__ B1,
    const short* __restrict__ B2,
    float* __restrict__ Cb, const int KT, const int N,
    const size_t sA, const size_t sB, const size_t sC)
{
    __shared__ f32x4 lds4[2 * S * 640];            // 2*S*10240 bytes
    char* lds = (char*)lds4;
    const int bx = blockIdx.x, by = blockIdx.y, bz = blockIdx.z;
    const int tid = threadIdx.x, lane = tid & 63, w = tid >> 6;
    const int wm = w >> 1, wn = w & 1;
    const size_t tA = (size_t)bz * sA + (size_t)by * KT * 5120;
    const size_t tB = (size_t)bz * sB + (size_t)bx * KT * 5120;

    // staging assignment: arrays 0..S-1 = A splits, S..2S-1 = B splits
    const short* s1; char* d1;
    const short* s2 = nullptr; char* d2 = nullptr;
    if constexpr (S == 2) {
        s1 = (w == 0 ? A0 : w == 1 ? A1 : w == 2 ? B0 : B1) + ((w < 2) ? tA : tB);
        d1 = lds + w * 10240;
    } else {
        s1 = (w == 0 ? A0 : w == 1 ? A1 : w == 2 ? A2 : B0) + ((w < 3) ? tA : tB);
        d1 = lds + w * 10240;
        if (w < 2) { s2 = (w == 0 ? B1 : B2) + tB; d2 = lds + (4 + w) * 10240; }
    }

    f32x4 acc[4][4];
    #pragma unroll
    for (int i = 0; i < 4; ++i)
        #pragma unroll
        for (int j = 0; j < 4; ++j) acc[i][j] = (f32x4){0.f, 0.f, 0.f, 0.f};

    const int fr = lane & 15;
    const int fkb = (lane >> 4) * 16;

    for (int kt = 0; kt < KT; ++kt) {
        const char* g1 = (const char*)(s1 + (size_t)kt * 5120);
        #pragma unroll
        for (int u = 0; u < 10; ++u)
            __builtin_amdgcn_global_load_lds(
                (const __attribute__((address_space(1))) unsigned int*)(g1 + u*1024 + lane*16),
                (__attribute__((address_space(3))) unsigned int*)(d1 + u*1024),
                16, 0, 0);
        if constexpr (S == 3) {
            if (w < 2) {
                const char* g2 = (const char*)(s2 + (size_t)kt * 5120);
                #pragma unroll
                for (int u = 0; u < 10; ++u)
                    __builtin_amdgcn_global_load_lds(
                        (const __attribute__((address_space(1))) unsigned int*)(g2 + u*1024 + lane*16),
                        (__attribute__((address_space(3))) unsigned int*)(d2 + u*1024),
                        16, 0, 0);
            }
        }
        __syncthreads();

        short8 bf[S][4];
        #pragma unroll
        for (int s = 0; s < S; ++s)
            #pragma unroll
            for (int ni = 0; ni < 4; ++ni) {
                const int r = wn*64 + ni*16 + fr;
                bf[s][ni] = *(const short8*)(lds + (S + s)*10240 + r*80 + fkb);
            }
        #pragma unroll
        for (int mi = 0; mi < 4; ++mi) {
            const int r = wm*64 + mi*16 + fr;
            short8 af[S];
            #pragma unroll
            for (int s = 0; s < S; ++s)
                af[s] = *(const short8*)(lds + s*10240 + r*80 + fkb);
            #pragma unroll
            for (int ni = 0; ni < 4; ++ni) {
                acc[mi][ni] = __builtin_amdgcn_mfma_f32_16x16x32_bf16(af[0], bf[0][ni], acc[mi][ni], 0, 0, 0);
                acc[mi][ni] = __builtin_amdgcn_mfma_f32_16x16x32_bf16(af[0], bf[1][ni], acc[mi][ni], 0, 0, 0);
                acc[mi][ni] = __builtin_amdgcn_mfma_f32_16x16x32_bf16(af[1], bf[0][ni], acc[mi][ni], 0, 0, 0);
                if constexpr (S == 3) {
                    acc[mi][ni] = __builtin_amdgcn_mfma_f32_16x16x32_bf16(af[0], bf[2][ni], acc[mi][ni], 0, 0, 0);
                    acc[mi][ni] = __builtin_amdgcn_mfma_f32_16x16x32_bf16(af[1], bf[1][ni], acc[mi][ni], 0, 0, 0);
                    acc[mi][ni] = __builtin_amdgcn_mfma_f32_16x16x32_bf16(af[2], bf[0][ni], acc[mi][ni], 0, 0, 0);
                }
            }
        }
        __syncthreads();
    }
    // epilogue: D col=lane&15, row=(lane>>4)*4+reg  [verified m89 mapping]
    float* C = Cb + (size_t)bz * sC;
    const int cr = (lane >> 4) * 4, cc = lane & 15;
    const int row0 = by*128 + wm*64, col0 = bx*128 + wn*64;
    #pragma unroll
    for (int mi = 0; mi < 4; ++mi)
        #pragma unroll
        for (int ni = 0; ni < 4; ++ni) {
            float* cp = C + (size_t)(row0 + mi*16 + cr) * N + col0 + ni*16 + cc;
            #pragma unroll
            for (int rg = 0; rg < 4; ++rg)
                cp[(size_t)rg * N] = acc[mi][ni][rg];
        }
}

// rcp[z][c] = 1 / max(sqrt(U[c][c]), 1e-4)
__global__ void diag_rcp(const float* __restrict__ U, float* __restrict__ rcp,
                         size_t sU) {
    int c = blockIdx.x * 256 + threadIdx.x;
    int z = blockIdx.y;
    if (c >= LP) return;
    rcp[z*LP + c] = 1.0f / fmaxf(sqrtf(U[(size_t)z*sU + (size_t)c * (LP + 1)]), 1e-4f);
}

// Row softmax over U[p][*] fused with masking, boost, clip, bf16 2-split.
// One wave per row p; writes V tiles [pby][ckt][r][40].
__global__ __launch_bounds__(256) void softmax_split(
    const float* __restrict__ Ub, const float* __restrict__ rcpb,
    const float* __restrict__ mmb, const float* __restrict__ mab,
    short* __restrict__ Vhi, short* __restrict__ Vlo,
    size_t sU, size_t sV)
{
    const int z = blockIdx.y;
    const int wid = threadIdx.x >> 6, lane = threadIdx.x & 63;
    const int p = blockIdx.x * 4 + wid;
    const float* U = Ub + (size_t)z * sU + (size_t)p * LP;
    const float* rcp = rcpb + z * LP;
    const float* mm = mmb + (size_t)z * LP;
    const float maP = mab[(size_t)z * LP + p];
    const float maS = maP * 10.0f;
    float t[9][4], mv[9][4];
    float mx = -INFINITY;
    #pragma unroll
    for (int i = 0; i < 9; ++i) {
        const int c = i * 256 + lane * 4;
        float4 u4 = *(const float4*)(U + c);
        float4 r4 = *(const float4*)(rcp + c);
        float4 m4 = *(const float4*)(mm + c);
        t[i][0] = u4.x * r4.x * m4.x * maS;  mv[i][0] = m4.x;
        t[i][1] = u4.y * r4.y * m4.y * maS;  mv[i][1] = m4.y;
        t[i][2] = u4.z * r4.z * m4.z * maS;  mv[i][2] = m4.z;
        t[i][3] = u4.w * r4.w * m4.w * maS;  mv[i][3] = m4.w;
        #pragma unroll
        for (int jj = 0; jj < 4; ++jj) mx = fmaxf(mx, t[i][jj]);
    }
    #pragma unroll
    for (int off = 32; off > 0; off >>= 1) mx = fmaxf(mx, __shfl_xor(mx, off, 64));
    float sm = 0.0f;
    #pragma unroll
    for (int i = 0; i < 9; ++i)
        #pragma unroll
        for (int jj = 0; jj < 4; ++jj) sm += __expf(t[i][jj] - mx);
    #pragma unroll
    for (int off = 32; off > 0; off >>= 1) sm += __shfl_xor(sm, off, 64);
    const float rS = 1.0f / sm;
    const int pi = p / W2, pj = p - pi * W2;
    const int pby = p >> 7, pr = p & 127;
    #pragma unroll
    for (int i = 0; i < 9; ++i) {
        const int c = i * 256 + lane * 4;
        short4v h4, l4;
        #pragma unroll
        for (int jj = 0; jj < 4; ++jj) {
            int cc = c + jj;
            float r = __expf(t[i][jj] - mx) * rS;
            int ci = cc / W2, cj = cc - ci * W2;
            if (abs(ci - pi) + abs(cj - pj) == 1) r = r + r * 0.5f;
            r = (r * mv[i][jj]) * maP;
            r = fmaxf(r, 1e-8f);
            unsigned short h = f2bf(r);
            unsigned short l = f2bf(r - bf2f(h));
            h4[jj] = (short)h; l4[jj] = (short)l;
        }
        size_t voff = ((size_t)(pby * 72 + (c >> 5)) * 128 + pr) * 40 + (c & 31);
        *(short4v*)(Vhi + (size_t)z * sV + voff) = h4;
        *(short4v*)(Vlo + (size_t)z * sV + voff) = l4;
    }
}

// y[z][ch][yy][xx] = 0.25 * sum over valid (ky,kx) of Z[(ch,ky,kx)][i*48+j]
__global__ void scatter_y(const float* __restrict__ Zb, float* __restrict__ yb,
                          size_t sZ, size_t sY) {
    int idx = blockIdx.x * 256 + threadIdx.x;
    int z = blockIdx.y;
    const float* Z = Zb + (size_t)z * sZ;
    int ch = idx / (H1*W1), r = idx % (H1*W1);
    int yy = r / W1, xx = r % W1;
    float s = 0.0f;
    #pragma unroll
    for (int ky = 0; ky < 4; ++ky) {
        int ny = yy + 1 - ky;
        if (ny & 1) continue;
        int i = ny >> 1;
        if ((unsigned)i >= H2) continue;
        #pragma unroll
        for (int kx = 0; kx < 4; ++kx) {
            int nx = xx + 1 - kx;
            if (nx & 1) continue;
            int j = nx >> 1;
            if ((unsigned)j >= W2) continue;
            s += Z[(size_t)(ch*16 + ky*4 + kx) * LP + i*W2 + j];
        }
    }
    yb[(size_t)z * sY + idx] = s * 0.25f;
}

// Dilated conv, IC-split 4x: block (bx = b*4*36 + g*36 + tile, by = ic chunk).
// Each block accumulates 32 ics into fp32 partials (no bias/relu).
__global__ __launch_bounds__(256) void dilated_conv_part(
    const float* __restrict__ y, const float* __restrict__ w,
    float* __restrict__ part) {
    int bid = blockIdx.x;                 // b*4*36 + g*36 + tile
    int tile = bid % 36; int g = (bid / 36) % 4; int b = bid / 144;
    int c4 = blockIdx.y;                  // ic chunk: [c4*32, c4*32+32)
    int yy = (tile / 6) * 16 + (threadIdx.x >> 4);
    int xx = (tile % 6) * 16 + (threadIdx.x & 15);
    int rr = 1 << g;                      // RATES = 1,2,4,8
    const float* yb = y + ((size_t)b * CCH + c4 * 32) * (H1 * W1);
    const float* wg = w + g * 16 * CCH * 9 + c4 * 32 * 9;
    float acc[16] = {};
    #pragma unroll 2
    for (int ic = 0; ic < 32; ++ic) {
        const float* yc = yb + ic * (H1 * W1);
        #pragma unroll
        for (int t = 0; t < 9; ++t) {
            int sy = yy + rr * (t / 3 - 1), sx = xx + rr * (t % 3 - 1);
            float v = 0.0f;
            if ((unsigned)sy < H1 && (unsigned)sx < W1) v = yc[sy*W1 + sx];
            #pragma unroll
            for (int oc = 0; oc < 16; ++oc)
                acc[oc] = fmaf(v, wg[(oc*CCH + ic)*9 + t], acc[oc]);
        }
    }
    // part layout: [c4][b][oc64][9216]
    float* pb = part + (((size_t)c4 * BATCH + b) * 64 + g * 16) * (H1 * W1)
                     + yy * W1 + xx;
    #pragma unroll
    for (int oc = 0; oc < 16; ++oc)
        pb[(size_t)oc * (H1 * W1)] = acc[oc];
}

// out[b][oc64][pix] = relu(sum_c4 part[c4][b][oc64][pix] + bias[oc64])
__global__ void conv_reduce(const float* __restrict__ part,
                            const float* __restrict__ bias,
                            float* __restrict__ out) {
    int idx = blockIdx.x * 256 + threadIdx.x;     // [0, 2*64*9216)
    int pix = idx % (H1 * W1);
    int rest = idx / (H1 * W1);
    int oc64 = rest % 64, b = rest / 64;
    const size_t st = (size_t)BATCH * 64 * (H1 * W1);
    size_t o = ((size_t)b * 64 + oc64) * (H1 * W1) + pix;
    float s = part[o] + part[st + o] + part[2*st + o] + part[3*st + o];
    out[o] = fmaxf(s + bias[oc64], 0.0f);
}

extern "C" void kernel_launch(void* const* d_in, const int* in_sizes, int n_in,
                              void* d_out, int out_size, void* d_ws, size_t ws_size,
                              hipStream_t stream) {
    const float* x1       = (const float*)d_in[0];
    const float* x2       = (const float*)d_in[1];
    const float* mask     = (const float*)d_in[2];
    const float* mask_all = (const float*)d_in[3];
    const float* conv_w   = (const float*)d_in[4];
    const float* conv_b   = (const float*)d_in[5];

    // per-batch element counts
    const size_t EA = 3317760;   // shorts: 18*36*128*40
    const size_t ER = 5898240;   // shorts: 16*72*128*40
    const size_t EV = 6635520;   // shorts: 18*72*128*40
    const size_t FU = 5308416;   // floats: 2304*2304
    const size_t FZ = 4718592;   // floats: 2048*2304
    const size_t FY = 2359296;   // floats: both batches of Y

    struct Offs { size_t A0, A1, A2, U, Rhi, Rlo, Z, Vhi, Vlo, Y, MS, MA, MM, RCP, need; };
    auto mk = [&](int NZ) {
        Offs o;
        o.A0 = 0;
        o.A1 = o.A0 + (size_t)NZ * EA * 2;
        o.A2 = o.A1 + (size_t)NZ * EA * 2;
        o.U  = o.A2 + (size_t)NZ * EA * 2;
        size_t endA = o.U + (size_t)NZ * FU * 4;
        o.Rhi = 0;                               // reuses A/U region (dead by then)
        o.Rlo = o.Rhi + (size_t)NZ * ER * 2;
        o.Z   = o.Rlo + (size_t)NZ * ER * 2;
        size_t endR = o.Z + (size_t)NZ * FZ * 4;
        size_t r1 = endA > endR ? endA : endR;
        o.Vhi = r1;
        o.Vlo = o.Vhi + (size_t)NZ * EV * 2;
        o.Y   = o.Vlo + (size_t)NZ * EV * 2;
        o.MS  = o.Y + FY * 4;
        o.MA  = o.MS + 4608 * 4;
        o.MM  = o.MA + 4608 * 4;
        o.RCP = o.MM + 4608 * 4;
        o.need = o.RCP + 4608 * 4;
        return o;
    };
    Offs o2 = mk(2), o1 = mk(1);
    if (ws_size < o1.need) return;               // fail loudly
    const int NZ = (ws_size >= o2.need) ? 2 : 1;
    Offs o = (NZ == 2) ? o2 : o1;

    char* base = (char*)d_ws;
    short* A0  = (short*)(base + o.A0);
    short* A1  = (short*)(base + o.A1);
    short* A2  = (short*)(base + o.A2);
    float* U   = (float*)(base + o.U);
    short* Rhi = (short*)(base + o.Rhi);
    short* Rlo = (short*)(base + o.Rlo);
    float* Z   = (float*)(base + o.Z);
    short* Vhi = (short*)(base + o.Vhi);
    short* Vlo = (short*)(base + o.Vlo);
    float* Y   = (float*)(base + o.Y);
    float* MS  = (float*)(base + o.MS);
    float* MA  = (float*)(base + o.MA);
    float* MM  = (float*)(base + o.MM);
    float* RCP = (float*)(base + o.RCP);
    // conv partials alias region-1 (A/U/R/Z all dead after last scatter_y):
    // 4 * 2 * 64 * 9216 floats = 18.9 MB << region-1 size in both NZ modes.
    float* PART = (float*)(base + 0);

    resize_masks<<<18, 256, 0, stream>>>(mask, mask_all, MS, MA);
    compute_mm<<<18, 256, 0, stream>>>(MS, MM);

    const size_t sX2 = (size_t)CCH * LP;
    const size_t sX1 = (size_t)CCH * H1 * W1;
    const size_t sYb = (size_t)CCH * H1 * W1;

    const int nIter = (NZ == 2) ? 1 : 2;
    for (int it = 0; it < nIter; ++it) {
        const int b0 = (NZ == 2) ? 0 : it;
        im2col_split3<<<dim3(10368, NZ), 256, 0, stream>>>(
            x2 + (size_t)b0 * sX2, A0, A1, A2, sX2, EA);
        gemm_mfma_split<3><<<dim3(18, 18, NZ), 256, 0, stream>>>(
            A0, A1, A2, A0, A1, A2, U, 36, LP, EA, EA, FU);
        diag_rcp<<<dim3(9, NZ), 256, 0, stream>>>(U, RCP, FU);
        softmax_split<<<dim3(576, NZ), 256, 0, stream>>>(
            U, RCP, MM + (size_t)b0 * LP, MA + (size_t)b0 * LP, Vhi, Vlo, FU, EV);
        rwt_split<<<dim3(18432, NZ), 256, 0, stream>>>(
            x1 + (size_t)b0 * sX1, Rhi, Rlo, sX1, ER);
        gemm_mfma_split<2><<<dim3(18, 16, NZ), 256, 0, stream>>>(
            Rhi, Rlo, nullptr, Vhi, Vlo, nullptr, Z, 72, LP, ER, EV, FZ);
        scatter_y<<<dim3(4608, NZ), 256, 0, stream>>>(
            Z, Y + (size_t)b0 * sYb, FZ, sYb);
    }
    dilated_conv_part<<<dim3(288, 4), 256, 0, stream>>>(Y, conv_w, PART);
    conv_reduce<<<4608, 256, 0, stream>>>(PART, conv_b, (float*)d_out);
}

// Round 9
// 527.869 us; speedup vs baseline: 4.0551x; 1.0897x over previous
//
#include <hip/hip_runtime.h>
#include <math.h>

// ---------------- problem constants ----------------
#define BATCH 2
#define CCH   128
#define H1    96
#define W1    96
#define H2    48
#define W2    48
#define LP    2304   // H2*W2
#define K1    1152   // CCH*9
#define M2    2048   // CCH*16

typedef __attribute__((ext_vector_type(8))) short short8;
typedef __attribute__((ext_vector_type(4))) float f32x4;
typedef __attribute__((ext_vector_type(4))) short short4v;

// bf16 helpers (RN-even)
__device__ __forceinline__ unsigned short f2bf(float x) {
    unsigned u = __float_as_uint(x);
    return (unsigned short)((u + 0x7fffu + ((u >> 16) & 1u)) >> 16);
}
__device__ __forceinline__ float bf2f(unsigned short h) {
    return __uint_as_float(((unsigned)h) << 16);
}

// ---------------- bilinear resize (exact jnp.linspace replication) ----------
__device__ __forceinline__ float lin_coord(int i) {
    if (i == 47) return 95.0f;
    return __fmul_rn(95.0f, __fdiv_rn((float)i, 47.0f));
}

__global__ void resize_masks(const float* __restrict__ mask,
                             const float* __restrict__ mask_all,
                             float* __restrict__ ms, float* __restrict__ ma) {
    int idx = blockIdx.x * 256 + threadIdx.x;
    if (idx >= BATCH * LP) return;
    int b = idx / LP, r = idx % LP;
    int i = r / W2, j = r % W2;
    float ys = lin_coord(i), xs = lin_coord(j);
    int y0 = (int)ys; int y1 = min(y0 + 1, 95);
    int x0 = (int)xs; int x1 = min(x0 + 1, 95);
    float wy = __fsub_rn(ys, (float)y0);
    float wx = __fsub_rn(xs, (float)x0);
    float wy1 = __fsub_rn(1.0f, wy), wx1 = __fsub_rn(1.0f, wx);
    const float* mb = mask + b * H1 * W1;
    float t0 = __fadd_rn(__fmul_rn(mb[y0*W1+x0], wy1), __fmul_rn(mb[y1*W1+x0], wy));
    float t1 = __fadd_rn(__fmul_rn(mb[y0*W1+x1], wy1), __fmul_rn(mb[y1*W1+x1], wy));
    ms[idx] = __fadd_rn(__fmul_rn(t0, wx1), __fmul_rn(t1, wx));
    const float* ab = mask_all + b * H1 * W1;
    t0 = __fadd_rn(__fmul_rn(ab[y0*W1+x0], wy1), __fmul_rn(ab[y1*W1+x0], wy));
    t1 = __fadd_rn(__fmul_rn(ab[y0*W1+x1], wy1), __fmul_rn(ab[y1*W1+x1], wy));
    ma[idx] = __fadd_rn(__fmul_rn(t0, wx1), __fmul_rn(t1, wx));
}

__global__ void compute_mm(const float* __restrict__ ms, float* __restrict__ mm) {
    int idx = blockIdx.x * 256 + threadIdx.x;
    if (idx >= BATCH * LP) return;
    int b = idx / LP, r = idx % LP;
    int ci = r / W2, cj = r % W2;
    const float* m = ms + b * LP;
    bool any = false;
    #pragma unroll
    for (int di = -1; di <= 1; ++di)
        #pragma unroll
        for (int dj = -1; dj <= 1; ++dj) {
            int y = ci + di, x = cj + dj;
            if ((unsigned)y < H2 && (unsigned)x < W2)
                any = any || (m[y*W2 + x] > 0.0f);
        }
    mm[idx] = any ? 0.0f : 1.0f;
}

// im2col of x2 into TRIPLE-split bf16 padded tiles: [by][kt][r=128][40 shorts]
__global__ void im2col_split3(const float* __restrict__ x2,
                              short* __restrict__ A0, short* __restrict__ A1,
                              short* __restrict__ A2,
                              size_t sIn, size_t sOut) {
    int idx = blockIdx.x * 256 + threadIdx.x;      // p*K1 + k
    int z = blockIdx.y;
    int p = idx / K1, k = idx - p * K1;
    int ch = k / 9, t = k - ch * 9, dy = t / 3, dx = t - dy * 3;
    int i = p / W2, j = p - i * W2;
    int y = i + dy - 1, x = j + dx - 1;
    float v = 0.0f;
    if ((unsigned)y < H2 && (unsigned)x < W2) v = x2[z*sIn + ch*LP + y*W2 + x];
    unsigned short h0 = f2bf(v);
    float r1 = v - bf2f(h0);
    unsigned short h1 = f2bf(r1);
    unsigned short h2 = f2bf(r1 - bf2f(h1));
    size_t off = ((size_t)((p >> 7) * 36 + (k >> 5)) * 128 + (p & 127)) * 40 + (k & 31);
    A0[z*sOut + off] = (short)h0;
    A1[z*sOut + off] = (short)h1;
    A2[z*sOut + off] = (short)h2;
}

// raw_w rows into 2-split bf16 padded tiles: [mby][ckt][r=128][40 shorts]
__global__ void rwt_split(const float* __restrict__ x1,
                          short* __restrict__ Rh, short* __restrict__ Rl,
                          size_t sIn, size_t sOut) {
    int idx = blockIdx.x * 256 + threadIdx.x;      // m*LP + c
    int z = blockIdx.y;
    int m = idx / LP, c = idx - m * LP;
    int ci = c / W2, cj = c - ci * W2;
    int ch = m >> 4, kk = m & 15, ky = kk >> 2, kx = kk & 3;
    int y = 2*ci + ky - 1, x = 2*cj + kx - 1;
    float v = 0.0f;
    if ((unsigned)y < H1 && (unsigned)x < W1) v = x1[z*sIn + (size_t)ch*H1*W1 + y*W1 + x];
    unsigned short h = f2bf(v);
    unsigned short l = f2bf(v - bf2f(h));
    size_t off = ((size_t)((m >> 7) * 72 + (c >> 5)) * 128 + (m & 127)) * 40 + (c & 31);
    Rh[z*sOut + off] = (short)h;
    Rl[z*sOut + off] = (short)l;
}

// ---------------- S-split bf16 MFMA GEMM ----------------
// C[m][n] = sum_k A[m][k]*B[n][k], A = sum A_s, B = sum B_s; products i+j<S.
// Tiles: [tile][kt][128][40 shorts]. 4 waves (2x2), wave 64x64, 16x16x32 frags.
// SYM: triangular grid (171 slots), mirror-store transpose; XCD-chunked order.
// !SYM: 288-slot grid remapped so each XCD (slot%8) owns a 9x4 tile region.
template <int S, bool SYM>
__global__ __launch_bounds__(256) void gemm_mfma_split(
    const short* __restrict__ A0, const short* __restrict__ A1,
    const short* __restrict__ A2,
    const short* __restrict__ B0, const short* __restrict__ B1,
    const short* __restrict__ B2,
    float* __restrict__ Cb, const int KT, const int N,
    const size_t sA, const size_t sB, const size_t sC)
{
    __shared__ f32x4 lds4[2 * S * 640];            // 2*S*10240 bytes
    char* lds = (char*)lds4;
    const int bz = blockIdx.z;
    int bx, by;
    if constexpr (SYM) {
        // slot -> XCD-chunked triangular tile (rows grouped per XCD)
        const int s = blockIdx.x;                  // 0..170
        const int k = s & 7, j = s >> 3;
        int t = 21 * k + min(k, 3) + j;
        int r = 0, rem = t;
        #pragma unroll
        for (int it = 0; it < 17; ++it) {
            int n = 18 - it;
            if (rem >= n) { rem -= n; ++r; } else break;
        }
        by = r; bx = by + rem;
    } else {
        // slot -> 9x4 region per XCD: grid 18x16 = 288 slots
        const int s = blockIdx.x;                  // 0..287
        const int k = s & 7, j = s >> 3;           // j in 0..35
        bx = (k & 1) * 9 + (j % 9);
        by = (k >> 1) * 4 + (j / 9);
    }
    const int tid = threadIdx.x, lane = tid & 63, w = tid >> 6;
    const int wm = w >> 1, wn = w & 1;
    const size_t tA = (size_t)bz * sA + (size_t)by * KT * 5120;
    const size_t tB = (size_t)bz * sB + (size_t)bx * KT * 5120;

    // staging assignment: arrays 0..S-1 = A splits, S..2S-1 = B splits
    const short* s1; char* d1;
    const short* s2 = nullptr; char* d2 = nullptr;
    if constexpr (S == 2) {
        s1 = (w == 0 ? A0 : w == 1 ? A1 : w == 2 ? B0 : B1) + ((w < 2) ? tA : tB);
        d1 = lds + w * 10240;
    } else {
        s1 = (w == 0 ? A0 : w == 1 ? A1 : w == 2 ? A2 : B0) + ((w < 3) ? tA : tB);
        d1 = lds + w * 10240;
        if (w < 2) { s2 = (w == 0 ? B1 : B2) + tB; d2 = lds + (4 + w) * 10240; }
    }

    f32x4 acc[4][4];
    #pragma unroll
    for (int i = 0; i < 4; ++i)
        #pragma unroll
        for (int j = 0; j < 4; ++j) acc[i][j] = (f32x4){0.f, 0.f, 0.f, 0.f};

    const int fr = lane & 15;
    const int fkb = (lane >> 4) * 16;

    for (int kt = 0; kt < KT; ++kt) {
        const char* g1 = (const char*)(s1 + (size_t)kt * 5120);
        #pragma unroll
        for (int u = 0; u < 10; ++u)
            __builtin_amdgcn_global_load_lds(
                (const __attribute__((address_space(1))) unsigned int*)(g1 + u*1024 + lane*16),
                (__attribute__((address_space(3))) unsigned int*)(d1 + u*1024),
                16, 0, 0);
        if constexpr (S == 3) {
            if (w < 2) {
                const char* g2 = (const char*)(s2 + (size_t)kt * 5120);
                #pragma unroll
                for (int u = 0; u < 10; ++u)
                    __builtin_amdgcn_global_load_lds(
                        (const __attribute__((address_space(1))) unsigned int*)(g2 + u*1024 + lane*16),
                        (__attribute__((address_space(3))) unsigned int*)(d2 + u*1024),
                        16, 0, 0);
            }
        }
        __syncthreads();

        short8 bf[S][4];
        #pragma unroll
        for (int s = 0; s < S; ++s)
            #pragma unroll
            for (int ni = 0; ni < 4; ++ni) {
                const int r = wn*64 + ni*16 + fr;
                bf[s][ni] = *(const short8*)(lds + (S + s)*10240 + r*80 + fkb);
            }
        #pragma unroll
        for (int mi = 0; mi < 4; ++mi) {
            const int r = wm*64 + mi*16 + fr;
            short8 af[S];
            #pragma unroll
            for (int s = 0; s < S; ++s)
                af[s] = *(const short8*)(lds + s*10240 + r*80 + fkb);
            #pragma unroll
            for (int ni = 0; ni < 4; ++ni) {
                acc[mi][ni] = __builtin_amdgcn_mfma_f32_16x16x32_bf16(af[0], bf[0][ni], acc[mi][ni], 0, 0, 0);
                acc[mi][ni] = __builtin_amdgcn_mfma_f32_16x16x32_bf16(af[0], bf[1][ni], acc[mi][ni], 0, 0, 0);
                acc[mi][ni] = __builtin_amdgcn_mfma_f32_16x16x32_bf16(af[1], bf[0][ni], acc[mi][ni], 0, 0, 0);
                if constexpr (S == 3) {
                    acc[mi][ni] = __builtin_amdgcn_mfma_f32_16x16x32_bf16(af[0], bf[2][ni], acc[mi][ni], 0, 0, 0);
                    acc[mi][ni] = __builtin_amdgcn_mfma_f32_16x16x32_bf16(af[1], bf[1][ni], acc[mi][ni], 0, 0, 0);
                    acc[mi][ni] = __builtin_amdgcn_mfma_f32_16x16x32_bf16(af[2], bf[0][ni], acc[mi][ni], 0, 0, 0);
                }
            }
        }
        __syncthreads();
    }
    // epilogue: D col=lane&15, row=(lane>>4)*4+reg  [verified m89 mapping]
    float* C = Cb + (size_t)bz * sC;
    const int cr = (lane >> 4) * 4, cc = lane & 15;
    const int row0 = by*128 + wm*64, col0 = bx*128 + wn*64;
    #pragma unroll
    for (int mi = 0; mi < 4; ++mi)
        #pragma unroll
        for (int ni = 0; ni < 4; ++ni) {
            float* cp = C + (size_t)(row0 + mi*16 + cr) * N + col0 + ni*16 + cc;
            #pragma unroll
            for (int rg = 0; rg < 4; ++rg)
                cp[(size_t)rg * N] = acc[mi][ni][rg];
        }
    if constexpr (SYM) {
        if (bx != by) {
            // mirror: C[n][m]; m = row0+mi*16+cr+rg is contiguous in rg -> float4
            #pragma unroll
            for (int mi = 0; mi < 4; ++mi)
                #pragma unroll
                for (int ni = 0; ni < 4; ++ni) {
                    const int n = col0 + ni*16 + cc;
                    float* mp = C + (size_t)n * N + row0 + mi*16 + cr;
                    *(float4*)mp = make_float4(acc[mi][ni][0], acc[mi][ni][1],
                                               acc[mi][ni][2], acc[mi][ni][3]);
                }
        }
    }
}

// rcp[z][c] = 1 / max(sqrt(U[c][c]), 1e-4)
__global__ void diag_rcp(const float* __restrict__ U, float* __restrict__ rcp,
                         size_t sU) {
    int c = blockIdx.x * 256 + threadIdx.x;
    int z = blockIdx.y;
    if (c >= LP) return;
    rcp[z*LP + c] = 1.0f / fmaxf(sqrtf(U[(size_t)z*sU + (size_t)c * (LP + 1)]), 1e-4f);
}

// Row softmax over U[p][*] fused with masking, boost, clip, bf16 2-split.
// One wave per row p; writes V tiles [pby][ckt][r][40].
__global__ __launch_bounds__(256) void softmax_split(
    const float* __restrict__ Ub, const float* __restrict__ rcpb,
    const float* __restrict__ mmb, const float* __restrict__ mab,
    short* __restrict__ Vhi, short* __restrict__ Vlo,
    size_t sU, size_t sV)
{
    const int z = blockIdx.y;
    const int wid = threadIdx.x >> 6, lane = threadIdx.x & 63;
    const int p = blockIdx.x * 4 + wid;
    const float* U = Ub + (size_t)z * sU + (size_t)p * LP;
    const float* rcp = rcpb + z * LP;
    const float* mm = mmb + (size_t)z * LP;
    const float maP = mab[(size_t)z * LP + p];
    const float maS = maP * 10.0f;
    float t[9][4], mv[9][4];
    float mx = -INFINITY;
    #pragma unroll
    for (int i = 0; i < 9; ++i) {
        const int c = i * 256 + lane * 4;
        float4 u4 = *(const float4*)(U + c);
        float4 r4 = *(const float4*)(rcp + c);
        float4 m4 = *(const float4*)(mm + c);
        t[i][0] = u4.x * r4.x * m4.x * maS;  mv[i][0] = m4.x;
        t[i][1] = u4.y * r4.y * m4.y * maS;  mv[i][1] = m4.y;
        t[i][2] = u4.z * r4.z * m4.z * maS;  mv[i][2] = m4.z;
        t[i][3] = u4.w * r4.w * m4.w * maS;  mv[i][3] = m4.w;
        #pragma unroll
        for (int jj = 0; jj < 4; ++jj) mx = fmaxf(mx, t[i][jj]);
    }
    #pragma unroll
    for (int off = 32; off > 0; off >>= 1) mx = fmaxf(mx, __shfl_xor(mx, off, 64));
    float sm = 0.0f;
    #pragma unroll
    for (int i = 0; i < 9; ++i)
        #pragma unroll
        for (int jj = 0; jj < 4; ++jj) sm += __expf(t[i][jj] - mx);
    #pragma unroll
    for (int off = 32; off > 0; off >>= 1) sm += __shfl_xor(sm, off, 64);
    const float rS = 1.0f / sm;
    const int pi = p / W2, pj = p - pi * W2;
    const int pby = p >> 7, pr = p & 127;
    #pragma unroll
    for (int i = 0; i < 9; ++i) {
        const int c = i * 256 + lane * 4;
        short4v h4, l4;
        #pragma unroll
        for (int jj = 0; jj < 4; ++jj) {
            int cc = c + jj;
            float r = __expf(t[i][jj] - mx) * rS;
            int ci = cc / W2, cj = cc - ci * W2;
            if (abs(ci - pi) + abs(cj - pj) == 1) r = r + r * 0.5f;
            r = (r * mv[i][jj]) * maP;
            r = fmaxf(r, 1e-8f);
            unsigned short h = f2bf(r);
            unsigned short l = f2bf(r - bf2f(h));
            h4[jj] = (short)h; l4[jj] = (short)l;
        }
        size_t voff = ((size_t)(pby * 72 + (c >> 5)) * 128 + pr) * 40 + (c & 31);
        *(short4v*)(Vhi + (size_t)z * sV + voff) = h4;
        *(short4v*)(Vlo + (size_t)z * sV + voff) = l4;
    }
}

// y[z][ch][yy][xx] = 0.25 * sum over valid (ky,kx) of Z[(ch,ky,kx)][i*48+j]
__global__ void scatter_y(const float* __restrict__ Zb, float* __restrict__ yb,
                          size_t sZ, size_t sY) {
    int idx = blockIdx.x * 256 + threadIdx.x;
    int z = blockIdx.y;
    const float* Z = Zb + (size_t)z * sZ;
    int ch = idx / (H1*W1), r = idx % (H1*W1);
    int yy = r / W1, xx = r % W1;
    float s = 0.0f;
    #pragma unroll
    for (int ky = 0; ky < 4; ++ky) {
        int ny = yy + 1 - ky;
        if (ny & 1) continue;
        int i = ny >> 1;
        if ((unsigned)i >= H2) continue;
        #pragma unroll
        for (int kx = 0; kx < 4; ++kx) {
            int nx = xx + 1 - kx;
            if (nx & 1) continue;
            int j = nx >> 1;
            if ((unsigned)j >= W2) continue;
            s += Z[(size_t)(ch*16 + ky*4 + kx) * LP + i*W2 + j];
        }
    }
    yb[(size_t)z * sY + idx] = s * 0.25f;
}

// Dilated conv, IC-split 4x: block (bx = b*4*36 + g*36 + tile, by = ic chunk).
__global__ __launch_bounds__(256) void dilated_conv_part(
    const float* __restrict__ y, const float* __restrict__ w,
    float* __restrict__ part) {
    int bid = blockIdx.x;                 // b*4*36 + g*36 + tile
    int tile = bid % 36; int g = (bid / 36) % 4; int b = bid / 144;
    int c4 = blockIdx.y;                  // ic chunk: [c4*32, c4*32+32)
    int yy = (tile / 6) * 16 + (threadIdx.x >> 4);
    int xx = (tile % 6) * 16 + (threadIdx.x & 15);
    int rr = 1 << g;                      // RATES = 1,2,4,8
    const float* yb = y + ((size_t)b * CCH + c4 * 32) * (H1 * W1);
    const float* wg = w + g * 16 * CCH * 9 + c4 * 32 * 9;
    float acc[16] = {};
    #pragma unroll 2
    for (int ic = 0; ic < 32; ++ic) {
        const float* yc = yb + ic * (H1 * W1);
        #pragma unroll
        for (int t = 0; t < 9; ++t) {
            int sy = yy + rr * (t / 3 - 1), sx = xx + rr * (t % 3 - 1);
            float v = 0.0f;
            if ((unsigned)sy < H1 && (unsigned)sx < W1) v = yc[sy*W1 + sx];
            #pragma unroll
            for (int oc = 0; oc < 16; ++oc)
                acc[oc] = fmaf(v, wg[(oc*CCH + ic)*9 + t], acc[oc]);
        }
    }
    // part layout: [c4][b][oc64][9216]
    float* pb = part + (((size_t)c4 * BATCH + b) * 64 + g * 16) * (H1 * W1)
                     + yy * W1 + xx;
    #pragma unroll
    for (int oc = 0; oc < 16; ++oc)
        pb[(size_t)oc * (H1 * W1)] = acc[oc];
}

// out[b][oc64][pix] = relu(sum_c4 part[c4][b][oc64][pix] + bias[oc64])
__global__ void conv_reduce(const float* __restrict__ part,
                            const float* __restrict__ bias,
                            float* __restrict__ out) {
    int idx = blockIdx.x * 256 + threadIdx.x;     // [0, 2*64*9216)
    int pix = idx % (H1 * W1);
    int rest = idx / (H1 * W1);
    int oc64 = rest % 64, b = rest / 64;
    const size_t st = (size_t)BATCH * 64 * (H1 * W1);
    size_t o = ((size_t)b * 64 + oc64) * (H1 * W1) + pix;
    float s = part[o] + part[st + o] + part[2*st + o] + part[3*st + o];
    out[o] = fmaxf(s + bias[oc64], 0.0f);
}

extern "C" void kernel_launch(void* const* d_in, const int* in_sizes, int n_in,
                              void* d_out, int out_size, void* d_ws, size_t ws_size,
                              hipStream_t stream) {
    const float* x1       = (const float*)d_in[0];
    const float* x2       = (const float*)d_in[1];
    const float* mask     = (const float*)d_in[2];
    const float* mask_all = (const float*)d_in[3];
    const float* conv_w   = (const float*)d_in[4];
    const float* conv_b   = (const float*)d_in[5];

    // per-batch element counts
    const size_t EA = 3317760;   // shorts: 18*36*128*40
    const size_t ER = 5898240;   // shorts: 16*72*128*40
    const size_t EV = 6635520;   // shorts: 18*72*128*40
    const size_t FU = 5308416;   // floats: 2304*2304
    const size_t FZ = 4718592;   // floats: 2048*2304
    const size_t FY = 2359296;   // floats: both batches of Y

    struct Offs { size_t A0, A1, A2, U, Rhi, Rlo, Z, Vhi, Vlo, Y, MS, MA, MM, RCP, need; };
    auto mk = [&](int NZ) {
        Offs o;
        o.A0 = 0;
        o.A1 = o.A0 + (size_t)NZ * EA * 2;
        o.A2 = o.A1 + (size_t)NZ * EA * 2;
        o.U  = o.A2 + (size_t)NZ * EA * 2;
        size_t endA = o.U + (size_t)NZ * FU * 4;
        o.Rhi = 0;                               // reuses A/U region (dead by then)
        o.Rlo = o.Rhi + (size_t)NZ * ER * 2;
        o.Z   = o.Rlo + (size_t)NZ * ER * 2;
        size_t endR = o.Z + (size_t)NZ * FZ * 4;
        size_t r1 = endA > endR ? endA : endR;
        o.Vhi = r1;
        o.Vlo = o.Vhi + (size_t)NZ * EV * 2;
        o.Y   = o.Vlo + (size_t)NZ * EV * 2;
        o.MS  = o.Y + FY * 4;
        o.MA  = o.MS + 4608 * 4;
        o.MM  = o.MA + 4608 * 4;
        o.RCP = o.MM + 4608 * 4;
        o.need = o.RCP + 4608 * 4;
        return o;
    };
    Offs o2 = mk(2), o1 = mk(1);
    if (ws_size < o1.need) return;               // fail loudly
    const int NZ = (ws_size >= o2.need) ? 2 : 1;
    Offs o = (NZ == 2) ? o2 : o1;

    char* base = (char*)d_ws;
    short* A0  = (short*)(base + o.A0);
    short* A1  = (short*)(base + o.A1);
    short* A2  = (short*)(base + o.A2);
    float* U   = (float*)(base + o.U);
    short* Rhi = (short*)(base + o.Rhi);
    short* Rlo = (short*)(base + o.Rlo);
    float* Z   = (float*)(base + o.Z);
    short* Vhi = (short*)(base + o.Vhi);
    short* Vlo = (short*)(base + o.Vlo);
    float* Y   = (float*)(base + o.Y);
    float* MS  = (float*)(base + o.MS);
    float* MA  = (float*)(base + o.MA);
    float* MM  = (float*)(base + o.MM);
    float* RCP = (float*)(base + o.RCP);
    // conv partials alias region-1 (A/U/R/Z all dead after last scatter_y)
    float* PART = (float*)(base + 0);

    resize_masks<<<18, 256, 0, stream>>>(mask, mask_all, MS, MA);
    compute_mm<<<18, 256, 0, stream>>>(MS, MM);

    const size_t sX2 = (size_t)CCH * LP;
    const size_t sX1 = (size_t)CCH * H1 * W1;
    const size_t sYb = (size_t)CCH * H1 * W1;

    const int nIter = (NZ == 2) ? 1 : 2;
    for (int it = 0; it < nIter; ++it) {
        const int b0 = (NZ == 2) ? 0 : it;
        im2col_split3<<<dim3(10368, NZ), 256, 0, stream>>>(
            x2 + (size_t)b0 * sX2, A0, A1, A2, sX2, EA);
        gemm_mfma_split<3, true><<<dim3(171, 1, NZ), 256, 0, stream>>>(
            A0, A1, A2, A0, A1, A2, U, 36, LP, EA, EA, FU);
        diag_rcp<<<dim3(9, NZ), 256, 0, stream>>>(U, RCP, FU);
        softmax_split<<<dim3(576, NZ), 256, 0, stream>>>(
            U, RCP, MM + (size_t)b0 * LP, MA + (size_t)b0 * LP, Vhi, Vlo, FU, EV);
        rwt_split<<<dim3(18432, NZ), 256, 0, stream>>>(
            x1 + (size_t)b0 * sX1, Rhi, Rlo, sX1, ER);
        gemm_mfma_split<2, false><<<dim3(288, 1, NZ), 256, 0, stream>>>(
            Rhi, Rlo, nullptr, Vhi, Vlo, nullptr, Z, 72, LP, ER, EV, FZ);
        scatter_y<<<dim3(4608, NZ), 256, 0, stream>>>(
            Z, Y + (size_t)b0 * sYb, FZ, sYb);
    }
    dilated_conv_part<<<dim3(288, 4), 256, 0, stream>>>(Y, conv_w, PART);
    conv_reduce<<<4608, 256, 0, stream>>>(PART, conv_b, (float*)d_out);
}